// Round 1
// 668.771 us; speedup vs baseline: 1.1918x; 1.1918x over previous
//
#include <hip/hip_runtime.h>

// SGGCN forward, round 5:
//  - CSR build reworked: 2-level bucketed counting sort (bucket = 256 dst nodes).
//    * bhist/bscan: bucket histogram + scan (tiny)
//    * filla: LDS-aggregated scatter into bucket-segmented tmp (run-claimed via one
//      global atomic per block*bucket -> mostly-full-line writes, no 8x amplification)
//    * fillb: per-bucket block; node-degree histogram + exclusive scan in LDS
//      (writes off[] directly -- deg_k and the 3 scan kernels are GONE), then
//      LDS-cursor scatter of epk within a 32KB L2-resident region.
//  - proj MLP fused: relu(h@pW1^T+pb1)@pW2^T+pb2 in ONE kernel, intermediate in LDS.

#define NF 128

using short8 = __attribute__((ext_vector_type(8))) short;
using f32x4  = __attribute__((ext_vector_type(4))) float;

__device__ __forceinline__ float b2f(unsigned short u) {
    return __uint_as_float(((unsigned)u) << 16);
}
__device__ __forceinline__ unsigned short f2b(float f) {
    unsigned u = __float_as_uint(f);
    u += 0x7fff + ((u >> 16) & 1);          // RNE
    return (unsigned short)(u >> 16);
}

// ================= CSR build (bucketed) =================
// bucket b = dst >> 8 (256 nodes per bucket). nbuk = ceil(N/256) = 391 for N=100K.
// tmp record: x = src | (dst&255)<<24  (src < 2^24), y = weight bits.

__global__ __launch_bounds__(256) void bhist_k(const int* __restrict__ ei,
                                               int* __restrict__ bhist,
                                               int E, int nbuk)
{
    __shared__ int cnt[512];
    int t = threadIdx.x;
    cnt[t] = 0; cnt[t + 256] = 0;
    __syncthreads();
    int e0 = blockIdx.x * 2048;
    int eend = min(e0 + 2048, E);
    for (int i = e0 + t; i < eend; i += 256)
        atomicAdd(&cnt[ei[E + i] >> 8], 1);
    __syncthreads();
    for (int b = t; b < nbuk; b += 256) {
        int c = cnt[b];
        if (c) atomicAdd(&bhist[b], c);
    }
}

__global__ __launch_bounds__(512) void bscan_k(const int* __restrict__ bhist,
                                               int* __restrict__ bbase,
                                               int* __restrict__ bcur, int nbuk)
{
    __shared__ int sc[512];
    int t = threadIdx.x;
    int v = (t < nbuk) ? bhist[t] : 0;
    sc[t] = v;
    __syncthreads();
    for (int ofs = 1; ofs < 512; ofs <<= 1) {
        int x = (t >= ofs) ? sc[t - ofs] : 0;
        __syncthreads();
        sc[t] += x;
        __syncthreads();
    }
    if (t < nbuk) {
        int ex = sc[t] - v;                 // exclusive
        bbase[t] = ex;
        bcur[t]  = ex;
    }
}

__global__ __launch_bounds__(256) void filla_k(const int* __restrict__ ei,
                                               const float* __restrict__ ew,
                                               int* __restrict__ bcur,
                                               int2* __restrict__ tmp, int E)
{
    __shared__ int dstg[2048];
    __shared__ int cnt[512];
    __shared__ int base[512];
    int t = threadIdx.x;
    cnt[t] = 0; cnt[t + 256] = 0;
    __syncthreads();
    int e0 = blockIdx.x * 2048;
    int eend = min(e0 + 2048, E);
    int n = eend - e0;
    for (int i = t; i < n; i += 256) {
        int d = ei[E + e0 + i];
        dstg[i] = d;
        atomicAdd(&cnt[d >> 8], 1);
    }
    __syncthreads();
    for (int b = t; b < 512; b += 256) {
        int c = cnt[b];
        base[b] = c ? atomicAdd(&bcur[b], c) : 0;  // claim contiguous run
        cnt[b] = 0;
    }
    __syncthreads();
    for (int i = t; i < n; i += 256) {
        int d = dstg[i];
        int b = d >> 8;
        int r = atomicAdd(&cnt[b], 1);             // LDS rank within run
        int2 q;
        q.x = (int)(((unsigned)ei[e0 + i]) | (((unsigned)(d & 255)) << 24));
        q.y = __float_as_int(ew[e0 + i]);
        tmp[base[b] + r] = q;
    }
}

__global__ __launch_bounds__(512) void fillb_k(const int2* __restrict__ tmp,
                                               const int* __restrict__ bbase,
                                               int* __restrict__ off,
                                               int2* __restrict__ epk,
                                               int N, int E, int nbuk)
{
    __shared__ int lcnt[256];
    __shared__ int lcur[256];
    int t = threadIdx.x;
    int b = blockIdx.x;
    int lo = b << 8;
    int nn = min(256, N - lo);
    if (t < 256) lcnt[t] = 0;
    __syncthreads();
    int s = bbase[b];
    int e_end = (b + 1 < nbuk) ? bbase[b + 1] : E;
    for (int i = s + t; i < e_end; i += 512)
        atomicAdd(&lcnt[((unsigned)tmp[i].x) >> 24], 1);
    __syncthreads();
    int v = (t < 256) ? lcnt[t] : 0;
    for (int ofs = 1; ofs < 256; ofs <<= 1) {       // inclusive Hillis-Steele
        int x = (t >= ofs && t < 256) ? lcnt[t - ofs] : 0;
        __syncthreads();
        if (t < 256) lcnt[t] += x;
        __syncthreads();
    }
    if (t < 256) {
        int st = s + lcnt[t] - v;                   // exclusive + bucket base
        lcur[t] = st;
        if (t < nn) off[lo + t] = st;               // off written here: no deg/scan
    }
    if (b == 0 && t == 0) off[N] = E;
    __syncthreads();
    for (int i = s + t; i < e_end; i += 512) {
        int2 q = tmp[i];
        unsigned qx = (unsigned)q.x;
        int pos = atomicAdd(&lcur[qx >> 24], 1);    // LDS cursor
        int2 o;
        o.x = (int)(qx & 0xFFFFFF);
        o.y = q.y;
        epk[pos] = o;
    }
}

// ================= converts =================
__global__ __launch_bounds__(256) void convx_k(const float* __restrict__ x,
                                               unsigned short* __restrict__ xb,
                                               int total4)
{
    int idx = blockIdx.x * 256 + threadIdx.x;
    if (idx >= total4) return;
    float4 v = *(const float4*)&x[(size_t)idx * 4];
    ushort4 o;
    o.x = f2b(v.x); o.y = f2b(v.y); o.z = f2b(v.z); o.w = f2b(v.w);
    *(ushort4*)&xb[(size_t)idx * 4] = o;
}

// W [M][128] fp32 -> frag-ordered bf16: Wb[((nb*4+ks)*64 + lane)*8 + j]
//   = W[nb*16 + (lane&15)][ks*32 + (lane>>4)*8 + j]
__global__ __launch_bounds__(64) void convw_k(const float* __restrict__ W,
                                              unsigned short* __restrict__ Wb)
{
    int lane = threadIdx.x;
    int nb = blockIdx.x >> 2, ks = blockIdx.x & 3;
    const float* src = W + (size_t)(nb * 16 + (lane & 15)) * 128 + ks * 32 + (lane >> 4) * 8;
    unsigned short* dst = Wb + ((size_t)blockIdx.x * 64 + lane) * 8;
#pragma unroll
    for (int j = 0; j < 8; j++) dst[j] = f2b(src[j]);
}

// ================= gather propagate (bf16 in/out, 128 cols) =================
__global__ __launch_bounds__(256) void gather_k(
    const unsigned short* __restrict__ h, const int* __restrict__ off,
    const int2* __restrict__ epk, unsigned short* __restrict__ p, int N,
    const float* __restrict__ bnstats, const float* __restrict__ g,
    const float* __restrict__ be, float invN)
{
    int row = blockIdx.x * 4 + (threadIdx.x >> 6);
    if (row >= N) return;
    int lane = threadIdx.x & 63;
    int c0 = lane * 2;

    float sc0 = 1.f, sh0 = 0.f, sc1 = 1.f, sh1 = 0.f;
    const bool bn = (bnstats != nullptr);
    if (bn) {
        float m0 = bnstats[c0] * invN;
        float v0 = bnstats[NF + c0] * invN - m0 * m0;
        float r0 = rsqrtf(v0 + 1e-5f) * g[c0];
        sc0 = r0; sh0 = be[c0] - m0 * r0;
        float m1 = bnstats[c0 + 1] * invN;
        float v1 = bnstats[NF + c0 + 1] * invN - m1 * m1;
        float r1 = rsqrtf(v1 + 1e-5f) * g[c0 + 1];
        sc1 = r1; sh1 = be[c0 + 1] - m1 * r1;
    }

    int beg = off[row], end = off[row + 1];
    float ax = 0.f, ay = 0.f;
    int e = beg;
    for (; e + 4 <= end; e += 4) {
        int2 q0 = epk[e + 0], q1 = epk[e + 1], q2 = epk[e + 2], q3 = epk[e + 3];
        ushort2 u0 = *(const ushort2*)&h[(size_t)q0.x * NF + c0];
        ushort2 u1 = *(const ushort2*)&h[(size_t)q1.x * NF + c0];
        ushort2 u2 = *(const ushort2*)&h[(size_t)q2.x * NF + c0];
        ushort2 u3 = *(const ushort2*)&h[(size_t)q3.x * NF + c0];
        float v0x = b2f(u0.x), v0y = b2f(u0.y);
        float v1x = b2f(u1.x), v1y = b2f(u1.y);
        float v2x = b2f(u2.x), v2y = b2f(u2.y);
        float v3x = b2f(u3.x), v3y = b2f(u3.y);
        if (bn) {
            v0x = fmaxf(fmaf(v0x, sc0, sh0), 0.f); v0y = fmaxf(fmaf(v0y, sc1, sh1), 0.f);
            v1x = fmaxf(fmaf(v1x, sc0, sh0), 0.f); v1y = fmaxf(fmaf(v1y, sc1, sh1), 0.f);
            v2x = fmaxf(fmaf(v2x, sc0, sh0), 0.f); v2y = fmaxf(fmaf(v2y, sc1, sh1), 0.f);
            v3x = fmaxf(fmaf(v3x, sc0, sh0), 0.f); v3y = fmaxf(fmaf(v3y, sc1, sh1), 0.f);
        }
        float w0 = __int_as_float(q0.y), w1 = __int_as_float(q1.y);
        float w2 = __int_as_float(q2.y), w3 = __int_as_float(q3.y);
        ax = fmaf(v0x, w0, ax); ay = fmaf(v0y, w0, ay);
        ax = fmaf(v1x, w1, ax); ay = fmaf(v1y, w1, ay);
        ax = fmaf(v2x, w2, ax); ay = fmaf(v2y, w2, ay);
        ax = fmaf(v3x, w3, ax); ay = fmaf(v3y, w3, ay);
    }
    for (; e < end; ++e) {
        int2 q = epk[e];
        float w = __int_as_float(q.y);
        ushort2 u = *(const ushort2*)&h[(size_t)q.x * NF + c0];
        float vx = b2f(u.x), vy = b2f(u.y);
        if (bn) {
            vx = fmaxf(fmaf(vx, sc0, sh0), 0.f);
            vy = fmaxf(fmaf(vy, sc1, sh1), 0.f);
        }
        ax = fmaf(vx, w, ax);
        ay = fmaf(vy, w, ay);
    }
    ushort2 o; o.x = f2b(ax); o.y = f2b(ay);
    *(ushort2*)&p[(size_t)row * NF + c0] = o;
}

// ============== gather over 64-dim bf16 rows -> fp32 logits + bias =========
__global__ __launch_bounds__(256) void gather64_k(
    const unsigned short* __restrict__ y, const int* __restrict__ off,
    const int2* __restrict__ epk, const float* __restrict__ bias,
    float* __restrict__ out, int N)
{
    int row = blockIdx.x * 8 + (threadIdx.x >> 5);
    if (row >= N) return;
    int sub = threadIdx.x & 31;
    int c0 = sub * 2;

    int beg = off[row], end = off[row + 1];
    float ax = 0.f, ay = 0.f;
    int e = beg;
    for (; e + 4 <= end; e += 4) {
        int2 q0 = epk[e + 0], q1 = epk[e + 1], q2 = epk[e + 2], q3 = epk[e + 3];
        ushort2 u0 = *(const ushort2*)&y[(size_t)q0.x * 64 + c0];
        ushort2 u1 = *(const ushort2*)&y[(size_t)q1.x * 64 + c0];
        ushort2 u2 = *(const ushort2*)&y[(size_t)q2.x * 64 + c0];
        ushort2 u3 = *(const ushort2*)&y[(size_t)q3.x * 64 + c0];
        float w0 = __int_as_float(q0.y), w1 = __int_as_float(q1.y);
        float w2 = __int_as_float(q2.y), w3 = __int_as_float(q3.y);
        ax = fmaf(b2f(u0.x), w0, ax); ay = fmaf(b2f(u0.y), w0, ay);
        ax = fmaf(b2f(u1.x), w1, ax); ay = fmaf(b2f(u1.y), w1, ay);
        ax = fmaf(b2f(u2.x), w2, ax); ay = fmaf(b2f(u2.y), w2, ay);
        ax = fmaf(b2f(u3.x), w3, ax); ay = fmaf(b2f(u3.y), w3, ay);
    }
    for (; e < end; ++e) {
        int2 q = epk[e];
        float w = __int_as_float(q.y);
        ushort2 u = *(const ushort2*)&y[(size_t)q.x * 64 + c0];
        ax = fmaf(b2f(u.x), w, ax);
        ay = fmaf(b2f(u.y), w, ay);
    }
    float2 o; o.x = ax + bias[c0]; o.y = ay + bias[c0 + 1];
    *(float2*)&out[(size_t)row * 64 + c0] = o;
}

// ================= MFMA GEMM: C[N,M] = A[N,128]bf16 @ W[M,128]^T + b ==========
template <int M, int COUT>
__global__ __launch_bounds__(256) void mgemm_k(
    const unsigned short* __restrict__ A, const unsigned short* __restrict__ Wb,
    const float* __restrict__ bias, void* __restrict__ Cp,
    int N, int relu, float* __restrict__ stats)
{
    constexpr int MI = (M == 128) ? 4 : 2;
    __shared__ float sbuf[256];

    const int tid = threadIdx.x, wid = tid >> 6, lane = tid & 63;
    const int quad = lane >> 4, l16 = lane & 15;
    const int rowBase = blockIdx.x * 128;
    int r0, c0;
    if constexpr (M == 128) { r0 = (wid >> 1) * 64; c0 = (wid & 1) * 64; }
    else                    { r0 = wid * 32;        c0 = 0; }

    f32x4 acc[MI][4];
#pragma unroll
    for (int mi = 0; mi < MI; mi++)
#pragma unroll
        for (int ni = 0; ni < 4; ni++)
#pragma unroll
            for (int r = 0; r < 4; r++) acc[mi][ni][r] = 0.f;

#pragma unroll
    for (int ks = 0; ks < 4; ++ks) {
        short8 af[MI], bf[4];
#pragma unroll
        for (int mi = 0; mi < MI; mi++) {
            int gr = rowBase + r0 + mi * 16 + l16;
            gr = (gr < N) ? gr : (N - 1);
            af[mi] = *(const short8*)(A + (size_t)gr * 128 + ks * 32 + quad * 8);
        }
#pragma unroll
        for (int ni = 0; ni < 4; ni++) {
            int nb = (c0 >> 4) + ni;
            bf[ni] = *(const short8*)(Wb + ((size_t)(nb * 4 + ks) * 64 + lane) * 8);
        }
#pragma unroll
        for (int mi = 0; mi < MI; mi++)
#pragma unroll
            for (int ni = 0; ni < 4; ni++)
                acc[mi][ni] = __builtin_amdgcn_mfma_f32_16x16x32_bf16(
                    af[mi], bf[ni], acc[mi][ni], 0, 0, 0);
    }

    float csum[4] = {0.f, 0.f, 0.f, 0.f}, csq[4] = {0.f, 0.f, 0.f, 0.f};
#pragma unroll
    for (int mi = 0; mi < MI; mi++) {
#pragma unroll
        for (int r = 0; r < 4; r++) {
            int gr = rowBase + r0 + mi * 16 + quad * 4 + r;
            if (gr >= N) continue;
#pragma unroll
            for (int ni = 0; ni < 4; ni++) {
                int col = c0 + ni * 16 + l16;
                float v = acc[mi][ni][r] + (bias ? bias[col] : 0.f);
                if (relu) v = fmaxf(v, 0.f);
                if constexpr (COUT == 1)
                    ((unsigned short*)Cp)[(size_t)gr * M + col] = f2b(v);
                else
                    ((float*)Cp)[(size_t)gr * M + col] = v;
                csum[ni] += v;
                csq[ni]  += v * v;
            }
        }
    }

    if (stats) {
        sbuf[tid] = 0.f;
        __syncthreads();
#pragma unroll
        for (int ni = 0; ni < 4; ni++) {
            int col = c0 + ni * 16 + l16;
            atomicAdd(&sbuf[col], csum[ni]);
            atomicAdd(&sbuf[128 + col], csq[ni]);
        }
        __syncthreads();
        if (tid < 128) {
            unsafeAtomicAdd(&stats[tid], sbuf[tid]);
            unsafeAtomicAdd(&stats[NF + tid], sbuf[128 + tid]);
        }
    }
}

// ====== fused proj MLP: Z = relu(A@W1^T + b1) @ W2^T + b2, LDS intermediate ====
__global__ __launch_bounds__(256) void projf_k(
    const unsigned short* __restrict__ A, const unsigned short* __restrict__ W1b,
    const float* __restrict__ bias1, const unsigned short* __restrict__ W2b,
    const float* __restrict__ bias2, float* __restrict__ Z, int N)
{
    __shared__ unsigned short tbuf[128][136];   // +8 pad: 16B-aligned, fewer conflicts

    const int tid = threadIdx.x, wid = tid >> 6, lane = tid & 63;
    const int quad = lane >> 4, l16 = lane & 15;
    const int rowBase = blockIdx.x * 128;
    const int r0 = (wid >> 1) * 64, c0 = (wid & 1) * 64;

    f32x4 acc[4][4];
#pragma unroll
    for (int mi = 0; mi < 4; mi++)
#pragma unroll
        for (int ni = 0; ni < 4; ni++)
#pragma unroll
            for (int r = 0; r < 4; r++) acc[mi][ni][r] = 0.f;

    // stage 1: relu(A@W1^T + b1) -> LDS (bf16)
#pragma unroll
    for (int ks = 0; ks < 4; ++ks) {
        short8 af[4], bf[4];
#pragma unroll
        for (int mi = 0; mi < 4; mi++) {
            int gr = rowBase + r0 + mi * 16 + l16;
            gr = (gr < N) ? gr : (N - 1);
            af[mi] = *(const short8*)(A + (size_t)gr * 128 + ks * 32 + quad * 8);
        }
#pragma unroll
        for (int ni = 0; ni < 4; ni++) {
            int nb = (c0 >> 4) + ni;
            bf[ni] = *(const short8*)(W1b + ((size_t)(nb * 4 + ks) * 64 + lane) * 8);
        }
#pragma unroll
        for (int mi = 0; mi < 4; mi++)
#pragma unroll
            for (int ni = 0; ni < 4; ni++)
                acc[mi][ni] = __builtin_amdgcn_mfma_f32_16x16x32_bf16(
                    af[mi], bf[ni], acc[mi][ni], 0, 0, 0);
    }
#pragma unroll
    for (int mi = 0; mi < 4; mi++)
#pragma unroll
        for (int r = 0; r < 4; r++) {
            int lr = r0 + mi * 16 + quad * 4 + r;
#pragma unroll
            for (int ni = 0; ni < 4; ni++) {
                int col = c0 + ni * 16 + l16;
                float v = fmaxf(acc[mi][ni][r] + bias1[col], 0.f);
                tbuf[lr][col] = f2b(v);
            }
        }
    __syncthreads();

    // stage 2: T@W2^T + b2 -> Z (fp32), A-frags from LDS
#pragma unroll
    for (int mi = 0; mi < 4; mi++)
#pragma unroll
        for (int ni = 0; ni < 4; ni++)
#pragma unroll
            for (int r = 0; r < 4; r++) acc[mi][ni][r] = 0.f;

#pragma unroll
    for (int ks = 0; ks < 4; ++ks) {
        short8 af[4], bf[4];
#pragma unroll
        for (int mi = 0; mi < 4; mi++)
            af[mi] = *(const short8*)&tbuf[r0 + mi * 16 + l16][ks * 32 + quad * 8];
#pragma unroll
        for (int ni = 0; ni < 4; ni++) {
            int nb = (c0 >> 4) + ni;
            bf[ni] = *(const short8*)(W2b + ((size_t)(nb * 4 + ks) * 64 + lane) * 8);
        }
#pragma unroll
        for (int mi = 0; mi < 4; mi++)
#pragma unroll
            for (int ni = 0; ni < 4; ni++)
                acc[mi][ni] = __builtin_amdgcn_mfma_f32_16x16x32_bf16(
                    af[mi], bf[ni], acc[mi][ni], 0, 0, 0);
    }
#pragma unroll
    for (int mi = 0; mi < 4; mi++)
#pragma unroll
        for (int r = 0; r < 4; r++) {
            int gr = rowBase + r0 + mi * 16 + quad * 4 + r;
            if (gr >= N) continue;
#pragma unroll
            for (int ni = 0; ni < 4; ni++) {
                int col = c0 + ni * 16 + l16;
                Z[(size_t)gr * 128 + col] = acc[mi][ni][r] + bias2[col];
            }
        }
}

// ======= BN2 + affine + ReLU: bf16 pre -> fp32 out_h AND bf16 hb ==========
__global__ __launch_bounds__(256) void bnrelu2_k(
    const unsigned short* __restrict__ pre, const float* __restrict__ stats,
    const float* __restrict__ g, const float* __restrict__ be,
    float* __restrict__ outh, unsigned short* __restrict__ hb,
    int total4, float invN)
{
    int idx = blockIdx.x * 256 + threadIdx.x;
    if (idx >= total4) return;
    int c = (idx * 4) & 127;
    ushort4 u = *(const ushort4*)&pre[(size_t)idx * 4];
    float in[4] = {b2f(u.x), b2f(u.y), b2f(u.z), b2f(u.w)};
    float o[4];
#pragma unroll
    for (int i = 0; i < 4; i++) {
        float m   = stats[c + i] * invN;
        float var = stats[NF + c + i] * invN - m * m;
        float rs  = rsqrtf(var + 1e-5f);
        o[i] = fmaxf((in[i] - m) * rs * g[c + i] + be[c + i], 0.f);
    }
    float4 f; f.x = o[0]; f.y = o[1]; f.z = o[2]; f.w = o[3];
    *(float4*)&outh[(size_t)idx * 4] = f;
    ushort4 h4;
    h4.x = f2b(o[0]); h4.y = f2b(o[1]); h4.z = f2b(o[2]); h4.w = f2b(o[3]);
    *(ushort4*)&hb[(size_t)idx * 4] = h4;
}

extern "C" void kernel_launch(void* const* d_in, const int* in_sizes, int n_in,
                              void* d_out, int out_size, void* d_ws, size_t ws_size,
                              hipStream_t stream)
{
    const float* x   = (const float*)d_in[0];
    const int*   ei  = (const int*)d_in[1];
    const float* ew  = (const float*)d_in[2];
    const float* W1  = (const float*)d_in[3];
    const float* b1  = (const float*)d_in[4];
    const float* W2  = (const float*)d_in[5];
    const float* b2  = (const float*)d_in[6];
    const float* W3  = (const float*)d_in[7];
    const float* b3  = (const float*)d_in[8];
    const float* g1  = (const float*)d_in[9];
    const float* be1 = (const float*)d_in[10];
    const float* g2  = (const float*)d_in[11];
    const float* be2 = (const float*)d_in[12];
    const float* pW1 = (const float*)d_in[13];
    const float* pb1 = (const float*)d_in[14];
    const float* pW2 = (const float*)d_in[15];
    const float* pb2 = (const float*)d_in[16];

    const int N = in_sizes[0] / NF;
    const int E = in_sizes[2];

    float* out_logits = (float*)d_out;
    float* out_h      = out_logits + (size_t)N * 64;
    float* out_z      = out_h + (size_t)N * NF;

    // ---- workspace layout ----
    const size_t rowsUS = (size_t)N * NF;          // ushorts per N*128 bf16 buf
    int2*           epk = (int2*)d_ws;                           // E*8 B
    unsigned short* B1  = (unsigned short*)(epk + E);            // xb -> pre2b
    unsigned short* B2  = B1 + rowsUS;                           // tmp -> p0/p1 -> hb
    unsigned short* B3  = B2 + rowsUS;                           // pre1 -> y
    float* stats1 = (float*)(B3 + rowsUS);                       // 256
    float* stats2 = stats1 + 256;                                // 256
    float* wconv  = stats2 + 256;            // 5 bf16 weight bufs (as ushort)
    unsigned short* W1b  = (unsigned short*)wconv;               // 128*128
    unsigned short* W2b  = W1b + 128 * 128;
    unsigned short* pW1b = W2b + 128 * 128;
    unsigned short* pW2b = pW1b + 128 * 128;
    unsigned short* W3b  = pW2b + 128 * 128;                     // 64*128
    int* off   = (int*)(W3b + 64 * 128);                         // N+1
    int* bhist = off + N + 1;                                    // 512
    int* bbase = bhist + 512;                                    // 512
    int* bcur  = bbase + 512;                                    // 512
    int2* tmp  = (int2*)B2;   // bucket-sorted intermediate (E*8B <= 25.6MB), freed
                              // before gather_k first writes B2 (serial stream)

    const int nbuk   = (N + 255) >> 8;
    const int ggrid  = (N + 127) / 128;
    const int pgrid  = (N + 3) / 4;
    const int p8grid = (N + 7) / 8;
    const int c4grid = (N * NF / 4 + 255) / 256;
    const int egrid  = (E + 2047) / 2048;
    const float invN = 1.f / (float)N;

    // ---- converts ----
    convx_k<<<c4grid, 256, 0, stream>>>(x, B1, N * NF / 4);
    convw_k<<<32, 64, 0, stream>>>(W1, W1b);
    convw_k<<<32, 64, 0, stream>>>(W2, W2b);
    convw_k<<<32, 64, 0, stream>>>(pW1, pW1b);
    convw_k<<<32, 64, 0, stream>>>(pW2, pW2b);
    convw_k<<<16, 64, 0, stream>>>(W3, W3b);

    // ---- CSR build (bucketed counting sort; no per-node global atomics) ----
    hipMemsetAsync(bhist, 0, 512 * sizeof(int), stream);
    bhist_k<<<egrid, 256, 0, stream>>>(ei, bhist, E, nbuk);
    bscan_k<<<1, 512, 0, stream>>>(bhist, bbase, bcur, nbuk);
    filla_k<<<egrid, 256, 0, stream>>>(ei, ew, bcur, tmp, E);
    fillb_k<<<nbuk, 512, 0, stream>>>(tmp, bbase, off, epk, N, E, nbuk);

    // ---- layer 1 ----
    gather_k<<<pgrid, 256, 0, stream>>>(B1, off, epk, B2, N,
                                        nullptr, nullptr, nullptr, 0.f);
    hipMemsetAsync(stats1, 0, 2 * NF * sizeof(float), stream);
    mgemm_k<128, 1><<<ggrid, 256, 0, stream>>>(B2, W1b, b1, B3, N, 0, stats1);

    // ---- layer 2 (BN1+ReLU fused into gather load) ----
    gather_k<<<pgrid, 256, 0, stream>>>(B3, off, epk, B2, N,
                                        stats1, g1, be1, invN);
    hipMemsetAsync(stats2, 0, 2 * NF * sizeof(float), stream);
    mgemm_k<128, 1><<<ggrid, 256, 0, stream>>>(B2, W2b, b2, B1, N, 0, stats2);

    // ---- BN2+ReLU -> out_h (fp32) + hb (bf16, into B2) ----
    bnrelu2_k<<<c4grid, 256, 0, stream>>>(B1, stats2, g2, be2, out_h, B2,
                                          N * NF / 4, invN);

    // ---- logits = propagate(h @ W3^T) + b3 ----
    mgemm_k<64, 1><<<ggrid, 256, 0, stream>>>(B2, W3b, nullptr, B3, N, 0, nullptr);
    gather64_k<<<p8grid, 256, 0, stream>>>(B3, off, epk, b3, out_logits, N);

    // ---- proj MLP fused: z = relu(h@pW1.T+pb1) @ pW2.T + pb2 ----
    projf_k<<<ggrid, 256, 0, stream>>>(B2, pW1b, pb1, pW2b, pb2, out_z, N);
}

// Round 5
// 651.770 us; speedup vs baseline: 1.2229x; 1.0261x over previous
//
#include <hip/hip_runtime.h>

// SGGCN forward, round 9 (= round-5 structure + wide gather + projf only):
//  - gmg_k (gather+GEMM fusion) ABANDONED: 3 rounds of run-varying 0.43-0.59
//    absmax localized to it by elimination; round-5 split path is stable 0.125.
//  - gather_k: 2 edge-streams per wave (32 lanes x ushort4 = 128 cols), 4-deep
//    unroll per stream -> 8 edges in flight, half the VMEM instr rate/edge.
//    Order-only change (tree sum); round0-vs-round5 proved order noise invisible.
//  - projf_k: fused proj MLP (writes ONLY out_z; z bit-identical to round 5).
//  - everything else: round-5 verbatim (CSR bucketed sort, mgemm, bnrelu2).

#define NF 128

using short8 = __attribute__((ext_vector_type(8))) short;
using f32x4  = __attribute__((ext_vector_type(4))) float;

__device__ __forceinline__ float b2f(unsigned short u) {
    return __uint_as_float(((unsigned)u) << 16);
}
__device__ __forceinline__ unsigned short f2b(float f) {
    unsigned u = __float_as_uint(f);
    u += 0x7fff + ((u >> 16) & 1);          // RNE
    return (unsigned short)(u >> 16);
}

// ================= CSR build (bucketed) =================
__global__ __launch_bounds__(256) void bhist_k(const int* __restrict__ ei,
                                               int* __restrict__ bhist,
                                               int E, int nbuk)
{
    __shared__ int cnt[512];
    int t = threadIdx.x;
    cnt[t] = 0; cnt[t + 256] = 0;
    __syncthreads();
    int e0 = blockIdx.x * 2048;
    int eend = min(e0 + 2048, E);
    for (int i = e0 + t; i < eend; i += 256)
        atomicAdd(&cnt[ei[E + i] >> 8], 1);
    __syncthreads();
    for (int b = t; b < nbuk; b += 256) {
        int c = cnt[b];
        if (c) atomicAdd(&bhist[b], c);
    }
}

__global__ __launch_bounds__(512) void bscan_k(const int* __restrict__ bhist,
                                               int* __restrict__ bbase,
                                               int* __restrict__ bcur, int nbuk)
{
    __shared__ int sc[512];
    int t = threadIdx.x;
    int v = (t < nbuk) ? bhist[t] : 0;
    sc[t] = v;
    __syncthreads();
    for (int ofs = 1; ofs < 512; ofs <<= 1) {
        int x = (t >= ofs) ? sc[t - ofs] : 0;
        __syncthreads();
        sc[t] += x;
        __syncthreads();
    }
    if (t < nbuk) {
        int ex = sc[t] - v;                 // exclusive
        bbase[t] = ex;
        bcur[t]  = ex;
    }
}

__global__ __launch_bounds__(256) void filla_k(const int* __restrict__ ei,
                                               const float* __restrict__ ew,
                                               int* __restrict__ bcur,
                                               int2* __restrict__ tmp, int E)
{
    __shared__ int dstg[2048];
    __shared__ int cnt[512];
    __shared__ int base[512];
    int t = threadIdx.x;
    cnt[t] = 0; cnt[t + 256] = 0;
    __syncthreads();
    int e0 = blockIdx.x * 2048;
    int eend = min(e0 + 2048, E);
    int n = eend - e0;
    for (int i = t; i < n; i += 256) {
        int d = ei[E + e0 + i];
        dstg[i] = d;
        atomicAdd(&cnt[d >> 8], 1);
    }
    __syncthreads();
    for (int b = t; b < 512; b += 256) {
        int c = cnt[b];
        base[b] = c ? atomicAdd(&bcur[b], c) : 0;  // claim contiguous run
        cnt[b] = 0;
    }
    __syncthreads();
    for (int i = t; i < n; i += 256) {
        int d = dstg[i];
        int b = d >> 8;
        int r = atomicAdd(&cnt[b], 1);             // LDS rank within run
        int2 q;
        q.x = (int)(((unsigned)ei[e0 + i]) | (((unsigned)(d & 255)) << 24));
        q.y = __float_as_int(ew[e0 + i]);
        tmp[base[b] + r] = q;
    }
}

__global__ __launch_bounds__(512) void fillb_k(const int2* __restrict__ tmp,
                                               const int* __restrict__ bbase,
                                               int* __restrict__ off,
                                               int2* __restrict__ epk,
                                               int N, int E, int nbuk)
{
    __shared__ int lcnt[256];
    __shared__ int lcur[256];
    int t = threadIdx.x;
    int b = blockIdx.x;
    int lo = b << 8;
    int nn = min(256, N - lo);
    if (t < 256) lcnt[t] = 0;
    __syncthreads();
    int s = bbase[b];
    int e_end = (b + 1 < nbuk) ? bbase[b + 1] : E;
    for (int i = s + t; i < e_end; i += 512)
        atomicAdd(&lcnt[((unsigned)tmp[i].x) >> 24], 1);
    __syncthreads();
    int v = (t < 256) ? lcnt[t] : 0;
    for (int ofs = 1; ofs < 256; ofs <<= 1) {       // inclusive Hillis-Steele
        int x = (t >= ofs && t < 256) ? lcnt[t - ofs] : 0;
        __syncthreads();
        if (t < 256) lcnt[t] += x;
        __syncthreads();
    }
    if (t < 256) {
        int st = s + lcnt[t] - v;                   // exclusive + bucket base
        lcur[t] = st;
        if (t < nn) off[lo + t] = st;
    }
    if (b == 0 && t == 0) off[N] = E;
    __syncthreads();
    for (int i = s + t; i < e_end; i += 512) {
        int2 q = tmp[i];
        unsigned qx = (unsigned)q.x;
        int pos = atomicAdd(&lcur[qx >> 24], 1);    // LDS cursor
        int2 o;
        o.x = (int)(qx & 0xFFFFFF);
        o.y = q.y;
        epk[pos] = o;
    }
}

// ================= converts =================
__global__ __launch_bounds__(256) void convx_k(const float* __restrict__ x,
                                               unsigned short* __restrict__ xb,
                                               int total4)
{
    int idx = blockIdx.x * 256 + threadIdx.x;
    if (idx >= total4) return;
    float4 v = *(const float4*)&x[(size_t)idx * 4];
    ushort4 o;
    o.x = f2b(v.x); o.y = f2b(v.y); o.z = f2b(v.z); o.w = f2b(v.w);
    *(ushort4*)&xb[(size_t)idx * 4] = o;
}

// W [M][128] fp32 -> frag-ordered bf16: Wb[((nb*4+ks)*64 + lane)*8 + j]
//   = W[nb*16 + (lane&15)][ks*32 + (lane>>4)*8 + j]
__global__ __launch_bounds__(64) void convw_k(const float* __restrict__ W,
                                              unsigned short* __restrict__ Wb)
{
    int lane = threadIdx.x;
    int nb = blockIdx.x >> 2, ks = blockIdx.x & 3;
    const float* src = W + (size_t)(nb * 16 + (lane & 15)) * 128 + ks * 32 + (lane >> 4) * 8;
    unsigned short* dst = Wb + ((size_t)blockIdx.x * 64 + lane) * 8;
#pragma unroll
    for (int j = 0; j < 8; j++) dst[j] = f2b(src[j]);
}

// ======== gather propagate, 2 edge-streams/wave (bf16 in/out, 128 cols) ========
// One row per wave (4 waves/block). Lanes split: half = lane>>5 picks the edge
// stream, sub = lane&31 covers 4 cols via ushort4. 4-deep unroll per stream ->
// 8 edges in flight. Streams combined with one shfl_xor(32) per accumulator.
template <int BN>
__global__ __launch_bounds__(256) void gather_k(
    const unsigned short* __restrict__ h, const int* __restrict__ off,
    const int2* __restrict__ epk, unsigned short* __restrict__ p, int N,
    const float* __restrict__ bnstats, const float* __restrict__ g,
    const float* __restrict__ be, float invN)
{
    int row = blockIdx.x * 4 + (threadIdx.x >> 6);
    if (row >= N) return;
    int lane = threadIdx.x & 63;
    int half = lane >> 5;
    int sub  = lane & 31;
    int c0 = sub * 4;

    float sc[4] = {1.f, 1.f, 1.f, 1.f}, sh[4] = {0.f, 0.f, 0.f, 0.f};
    if (BN) {
#pragma unroll
        for (int j = 0; j < 4; j++) {
            float m = bnstats[c0 + j] * invN;
            float v = bnstats[NF + c0 + j] * invN - m * m;
            float r = rsqrtf(v + 1e-5f) * g[c0 + j];
            sc[j] = r; sh[j] = be[c0 + j] - m * r;
        }
    }

    int beg = off[row], end = off[row + 1];
    float a0 = 0.f, a1 = 0.f, a2 = 0.f, a3 = 0.f;

#define PROC_EDGE(qq, uu)                                                     \
    {                                                                         \
        float w = __int_as_float((qq).y);                                     \
        float vx = b2f((uu).x), vy = b2f((uu).y);                             \
        float vz = b2f((uu).z), vw = b2f((uu).w);                             \
        if (BN) {                                                             \
            vx = fmaxf(fmaf(vx, sc[0], sh[0]), 0.f);                          \
            vy = fmaxf(fmaf(vy, sc[1], sh[1]), 0.f);                          \
            vz = fmaxf(fmaf(vz, sc[2], sh[2]), 0.f);                          \
            vw = fmaxf(fmaf(vw, sc[3], sh[3]), 0.f);                          \
        }                                                                     \
        a0 = fmaf(vx, w, a0); a1 = fmaf(vy, w, a1);                           \
        a2 = fmaf(vz, w, a2); a3 = fmaf(vw, w, a3);                           \
    }

    int e = beg;
    for (; e + 8 <= end; e += 8) {
        int2 q0 = epk[e + 0 + half], q1 = epk[e + 2 + half];
        int2 q2 = epk[e + 4 + half], q3 = epk[e + 6 + half];
        ushort4 u0 = *(const ushort4*)&h[(size_t)q0.x * NF + c0];
        ushort4 u1 = *(const ushort4*)&h[(size_t)q1.x * NF + c0];
        ushort4 u2 = *(const ushort4*)&h[(size_t)q2.x * NF + c0];
        ushort4 u3 = *(const ushort4*)&h[(size_t)q3.x * NF + c0];
        PROC_EDGE(q0, u0); PROC_EDGE(q1, u1);
        PROC_EDGE(q2, u2); PROC_EDGE(q3, u3);
    }
    for (; e + 2 <= end; e += 2) {
        int2 q = epk[e + half];
        ushort4 u = *(const ushort4*)&h[(size_t)q.x * NF + c0];
        PROC_EDGE(q, u);
    }
    if (e < end && half == 0) {                       // odd tail: stream 0 only
        int2 q = epk[e];
        ushort4 u = *(const ushort4*)&h[(size_t)q.x * NF + c0];
        PROC_EDGE(q, u);
    }
#undef PROC_EDGE

    a0 += __shfl_xor(a0, 32);
    a1 += __shfl_xor(a1, 32);
    a2 += __shfl_xor(a2, 32);
    a3 += __shfl_xor(a3, 32);

    if (half == 0) {
        ushort4 o;
        o.x = f2b(a0); o.y = f2b(a1); o.z = f2b(a2); o.w = f2b(a3);
        *(ushort4*)&p[(size_t)row * NF + c0] = o;
    }
}

// ============== gather over 64-dim bf16 rows -> fp32 logits + bias =========
__global__ __launch_bounds__(256) void gather64_k(
    const unsigned short* __restrict__ y, const int* __restrict__ off,
    const int2* __restrict__ epk, const float* __restrict__ bias,
    float* __restrict__ out, int N)
{
    int row = blockIdx.x * 8 + (threadIdx.x >> 5);
    if (row >= N) return;
    int sub = threadIdx.x & 31;
    int c0 = sub * 2;

    int beg = off[row], end = off[row + 1];
    float ax = 0.f, ay = 0.f;
    int e = beg;
    for (; e + 4 <= end; e += 4) {
        int2 q0 = epk[e + 0], q1 = epk[e + 1], q2 = epk[e + 2], q3 = epk[e + 3];
        ushort2 u0 = *(const ushort2*)&y[(size_t)q0.x * 64 + c0];
        ushort2 u1 = *(const ushort2*)&y[(size_t)q1.x * 64 + c0];
        ushort2 u2 = *(const ushort2*)&y[(size_t)q2.x * 64 + c0];
        ushort2 u3 = *(const ushort2*)&y[(size_t)q3.x * 64 + c0];
        float w0 = __int_as_float(q0.y), w1 = __int_as_float(q1.y);
        float w2 = __int_as_float(q2.y), w3 = __int_as_float(q3.y);
        ax = fmaf(b2f(u0.x), w0, ax); ay = fmaf(b2f(u0.y), w0, ay);
        ax = fmaf(b2f(u1.x), w1, ax); ay = fmaf(b2f(u1.y), w1, ay);
        ax = fmaf(b2f(u2.x), w2, ax); ay = fmaf(b2f(u2.y), w2, ay);
        ax = fmaf(b2f(u3.x), w3, ax); ay = fmaf(b2f(u3.y), w3, ay);
    }
    for (; e < end; ++e) {
        int2 q = epk[e];
        float w = __int_as_float(q.y);
        ushort2 u = *(const ushort2*)&y[(size_t)q.x * 64 + c0];
        ax = fmaf(b2f(u.x), w, ax);
        ay = fmaf(b2f(u.y), w, ay);
    }
    float2 o; o.x = ax + bias[c0]; o.y = ay + bias[c0 + 1];
    *(float2*)&out[(size_t)row * 64 + c0] = o;
}

// ================= MFMA GEMM: C[N,M] = A[N,128]bf16 @ W[M,128]^T + b ==========
// (round-5 verbatim)
template <int M, int COUT>
__global__ __launch_bounds__(256) void mgemm_k(
    const unsigned short* __restrict__ A, const unsigned short* __restrict__ Wb,
    const float* __restrict__ bias, void* __restrict__ Cp,
    int N, int relu, float* __restrict__ stats)
{
    constexpr int MI = (M == 128) ? 4 : 2;
    __shared__ float sbuf[256];

    const int tid = threadIdx.x, wid = tid >> 6, lane = tid & 63;
    const int quad = lane >> 4, l16 = lane & 15;
    const int rowBase = blockIdx.x * 128;
    int r0, c0;
    if constexpr (M == 128) { r0 = (wid >> 1) * 64; c0 = (wid & 1) * 64; }
    else                    { r0 = wid * 32;        c0 = 0; }

    f32x4 acc[MI][4];
#pragma unroll
    for (int mi = 0; mi < MI; mi++)
#pragma unroll
        for (int ni = 0; ni < 4; ni++)
#pragma unroll
            for (int r = 0; r < 4; r++) acc[mi][ni][r] = 0.f;

#pragma unroll
    for (int ks = 0; ks < 4; ++ks) {
        short8 af[MI], bf[4];
#pragma unroll
        for (int mi = 0; mi < MI; mi++) {
            int gr = rowBase + r0 + mi * 16 + l16;
            gr = (gr < N) ? gr : (N - 1);
            af[mi] = *(const short8*)(A + (size_t)gr * 128 + ks * 32 + quad * 8);
        }
#pragma unroll
        for (int ni = 0; ni < 4; ni++) {
            int nb = (c0 >> 4) + ni;
            bf[ni] = *(const short8*)(Wb + ((size_t)(nb * 4 + ks) * 64 + lane) * 8);
        }
#pragma unroll
        for (int mi = 0; mi < MI; mi++)
#pragma unroll
            for (int ni = 0; ni < 4; ni++)
                acc[mi][ni] = __builtin_amdgcn_mfma_f32_16x16x32_bf16(
                    af[mi], bf[ni], acc[mi][ni], 0, 0, 0);
    }

    float csum[4] = {0.f, 0.f, 0.f, 0.f}, csq[4] = {0.f, 0.f, 0.f, 0.f};
#pragma unroll
    for (int mi = 0; mi < MI; mi++) {
#pragma unroll
        for (int r = 0; r < 4; r++) {
            int gr = rowBase + r0 + mi * 16 + quad * 4 + r;
            if (gr >= N) continue;
#pragma unroll
            for (int ni = 0; ni < 4; ni++) {
                int col = c0 + ni * 16 + l16;
                float v = acc[mi][ni][r] + (bias ? bias[col] : 0.f);
                if (relu) v = fmaxf(v, 0.f);
                if constexpr (COUT == 1)
                    ((unsigned short*)Cp)[(size_t)gr * M + col] = f2b(v);
                else
                    ((float*)Cp)[(size_t)gr * M + col] = v;
                csum[ni] += v;
                csq[ni]  += v * v;
            }
        }
    }

    if (stats) {
        sbuf[tid] = 0.f;
        __syncthreads();
#pragma unroll
        for (int ni = 0; ni < 4; ni++) {
            int col = c0 + ni * 16 + l16;
            atomicAdd(&sbuf[col], csum[ni]);
            atomicAdd(&sbuf[128 + col], csq[ni]);
        }
        __syncthreads();
        if (tid < 128) {
            unsafeAtomicAdd(&stats[tid], sbuf[tid]);
            unsafeAtomicAdd(&stats[NF + tid], sbuf[128 + tid]);
        }
    }
}

// ======= BN2 + affine + ReLU: bf16 pre -> fp32 out_h AND bf16 hb ==========
// (round-5 verbatim)
__global__ __launch_bounds__(256) void bnrelu2_k(
    const unsigned short* __restrict__ pre, const float* __restrict__ stats,
    const float* __restrict__ g, const float* __restrict__ be,
    float* __restrict__ outh, unsigned short* __restrict__ hb,
    int total4, float invN)
{
    int idx = blockIdx.x * 256 + threadIdx.x;
    if (idx >= total4) return;
    int c = (idx * 4) & 127;
    ushort4 u = *(const ushort4*)&pre[(size_t)idx * 4];
    float in[4] = {b2f(u.x), b2f(u.y), b2f(u.z), b2f(u.w)};
    float o[4];
#pragma unroll
    for (int i = 0; i < 4; i++) {
        float m   = stats[c + i] * invN;
        float var = stats[NF + c + i] * invN - m * m;
        float rs  = rsqrtf(var + 1e-5f);
        o[i] = fmaxf((in[i] - m) * rs * g[c + i] + be[c + i], 0.f);
    }
    float4 f; f.x = o[0]; f.y = o[1]; f.z = o[2]; f.w = o[3];
    *(float4*)&outh[(size_t)idx * 4] = f;
    ushort4 h4;
    h4.x = f2b(o[0]); h4.y = f2b(o[1]); h4.z = f2b(o[2]); h4.w = f2b(o[3]);
    *(ushort4*)&hb[(size_t)idx * 4] = h4;
}

// ====== fused proj MLP: Z = relu(A@W1^T + b1) @ W2^T + b2, LDS intermediate ====
// Writes ONLY out_z; tbuf holds the same bf16 values the round-5 global
// round-trip held -> z bit-identical.
__global__ __launch_bounds__(256) void projf_k(
    const unsigned short* __restrict__ A, const unsigned short* __restrict__ W1b,
    const float* __restrict__ bias1, const unsigned short* __restrict__ W2b,
    const float* __restrict__ bias2, float* __restrict__ Z, int N)
{
    __shared__ unsigned short tbuf[128][136];

    const int tid = threadIdx.x, wid = tid >> 6, lane = tid & 63;
    const int quad = lane >> 4, l16 = lane & 15;
    const int rowBase = blockIdx.x * 128;
    const int r0 = (wid >> 1) * 64, c0 = (wid & 1) * 64;

    f32x4 acc[4][4];
#pragma unroll
    for (int mi = 0; mi < 4; mi++)
#pragma unroll
        for (int ni = 0; ni < 4; ni++)
#pragma unroll
            for (int r = 0; r < 4; r++) acc[mi][ni][r] = 0.f;

    // stage 1: relu(A@W1^T + b1) -> LDS (bf16)
#pragma unroll
    for (int ks = 0; ks < 4; ++ks) {
        short8 af[4], bf[4];
#pragma unroll
        for (int mi = 0; mi < 4; mi++) {
            int gr = rowBase + r0 + mi * 16 + l16;
            gr = (gr < N) ? gr : (N - 1);
            af[mi] = *(const short8*)(A + (size_t)gr * 128 + ks * 32 + quad * 8);
        }
#pragma unroll
        for (int ni = 0; ni < 4; ni++) {
            int nb = (c0 >> 4) + ni;
            bf[ni] = *(const short8*)(W1b + ((size_t)(nb * 4 + ks) * 64 + lane) * 8);
        }
#pragma unroll
        for (int mi = 0; mi < 4; mi++)
#pragma unroll
            for (int ni = 0; ni < 4; ni++)
                acc[mi][ni] = __builtin_amdgcn_mfma_f32_16x16x32_bf16(
                    af[mi], bf[ni], acc[mi][ni], 0, 0, 0);
    }
#pragma unroll
    for (int mi = 0; mi < 4; mi++)
#pragma unroll
        for (int r = 0; r < 4; r++) {
            int lr = r0 + mi * 16 + quad * 4 + r;
#pragma unroll
            for (int ni = 0; ni < 4; ni++) {
                int col = c0 + ni * 16 + l16;
                float v = fmaxf(acc[mi][ni][r] + bias1[col], 0.f);
                tbuf[lr][col] = f2b(v);
            }
        }
    __syncthreads();

    // stage 2: T@W2^T + b2 -> Z (fp32), A-frags from LDS
#pragma unroll
    for (int mi = 0; mi < 4; mi++)
#pragma unroll
        for (int ni = 0; ni < 4; ni++)
#pragma unroll
            for (int r = 0; r < 4; r++) acc[mi][ni][r] = 0.f;

#pragma unroll
    for (int ks = 0; ks < 4; ++ks) {
        short8 af[4], bf[4];
#pragma unroll
        for (int mi = 0; mi < 4; mi++)
            af[mi] = *(const short8*)&tbuf[r0 + mi * 16 + l16][ks * 32 + quad * 8];
#pragma unroll
        for (int ni = 0; ni < 4; ni++) {
            int nb = (c0 >> 4) + ni;
            bf[ni] = *(const short8*)(W2b + ((size_t)(nb * 4 + ks) * 64 + lane) * 8);
        }
#pragma unroll
        for (int mi = 0; mi < 4; mi++)
#pragma unroll
            for (int ni = 0; ni < 4; ni++)
                acc[mi][ni] = __builtin_amdgcn_mfma_f32_16x16x32_bf16(
                    af[mi], bf[ni], acc[mi][ni], 0, 0, 0);
    }
#pragma unroll
    for (int mi = 0; mi < 4; mi++)
#pragma unroll
        for (int r = 0; r < 4; r++) {
            int gr = rowBase + r0 + mi * 16 + quad * 4 + r;
            if (gr >= N) continue;
#pragma unroll
            for (int ni = 0; ni < 4; ni++) {
                int col = c0 + ni * 16 + l16;
                Z[(size_t)gr * 128 + col] = acc[mi][ni][r] + bias2[col];
            }
        }
}

extern "C" void kernel_launch(void* const* d_in, const int* in_sizes, int n_in,
                              void* d_out, int out_size, void* d_ws, size_t ws_size,
                              hipStream_t stream)
{
    const float* x   = (const float*)d_in[0];
    const int*   ei  = (const int*)d_in[1];
    const float* ew  = (const float*)d_in[2];
    const float* W1  = (const float*)d_in[3];
    const float* b1  = (const float*)d_in[4];
    const float* W2  = (const float*)d_in[5];
    const float* b2  = (const float*)d_in[6];
    const float* W3  = (const float*)d_in[7];
    const float* b3  = (const float*)d_in[8];
    const float* g1  = (const float*)d_in[9];
    const float* be1 = (const float*)d_in[10];
    const float* g2  = (const float*)d_in[11];
    const float* be2 = (const float*)d_in[12];
    const float* pW1 = (const float*)d_in[13];
    const float* pb1 = (const float*)d_in[14];
    const float* pW2 = (const float*)d_in[15];
    const float* pb2 = (const float*)d_in[16];

    const int N = in_sizes[0] / NF;
    const int E = in_sizes[2];

    float* out_logits = (float*)d_out;
    float* out_h      = out_logits + (size_t)N * 64;
    float* out_z      = out_h + (size_t)N * NF;

    // ---- workspace layout (round-5) ----
    const size_t rowsUS = (size_t)N * NF;
    int2*           epk = (int2*)d_ws;                           // E*8 B
    unsigned short* B1  = (unsigned short*)(epk + E);            // xb -> pre2b
    unsigned short* B2  = B1 + rowsUS;                           // tmp -> p0/p1 -> hb
    unsigned short* B3  = B2 + rowsUS;                           // pre1 -> y -> t
    float* stats1 = (float*)(B3 + rowsUS);                       // 256
    float* stats2 = stats1 + 256;                                // 256
    float* wconv  = stats2 + 256;
    unsigned short* W1b  = (unsigned short*)wconv;               // 128*128
    unsigned short* W2b  = W1b + 128 * 128;
    unsigned short* pW1b = W2b + 128 * 128;
    unsigned short* pW2b = pW1b + 128 * 128;
    unsigned short* W3b  = pW2b + 128 * 128;                     // 64*128
    int* off   = (int*)(W3b + 64 * 128);                         // N+1
    int* bhist = off + N + 1;                                    // 512
    int* bbase = bhist + 512;                                    // 512
    int* bcur  = bbase + 512;                                    // 512
    int2* tmp  = (int2*)B2;   // bucket-sorted intermediate; dead before the
                              // first gather writes B2 (serial stream)

    const int nbuk   = (N + 255) >> 8;
    const int ggrid  = (N + 127) / 128;
    const int pgrid  = (N + 3) / 4;
    const int p8grid = (N + 7) / 8;
    const int c4grid = (N * NF / 4 + 255) / 256;
    const int egrid  = (E + 2047) / 2048;
    const float invN = 1.f / (float)N;

    // ---- converts ----
    convx_k<<<c4grid, 256, 0, stream>>>(x, B1, N * NF / 4);
    convw_k<<<32, 64, 0, stream>>>(W1, W1b);
    convw_k<<<32, 64, 0, stream>>>(W2, W2b);
    convw_k<<<32, 64, 0, stream>>>(pW1, pW1b);
    convw_k<<<32, 64, 0, stream>>>(pW2, pW2b);
    convw_k<<<16, 64, 0, stream>>>(W3, W3b);

    // ---- CSR build (bucketed counting sort) ----
    hipMemsetAsync(bhist, 0, 512 * sizeof(int), stream);
    bhist_k<<<egrid, 256, 0, stream>>>(ei, bhist, E, nbuk);
    bscan_k<<<1, 512, 0, stream>>>(bhist, bbase, bcur, nbuk);
    filla_k<<<egrid, 256, 0, stream>>>(ei, ew, bcur, tmp, E);
    fillb_k<<<nbuk, 512, 0, stream>>>(tmp, bbase, off, epk, N, E, nbuk);

    // ---- layer 1 ----
    gather_k<0><<<pgrid, 256, 0, stream>>>(B1, off, epk, B2, N,
                                           nullptr, nullptr, nullptr, 0.f);
    hipMemsetAsync(stats1, 0, 2 * NF * sizeof(float), stream);
    mgemm_k<128, 1><<<ggrid, 256, 0, stream>>>(B2, W1b, b1, B3, N, 0, stats1);

    // ---- layer 2 (BN1+ReLU fused into gather load) ----
    gather_k<1><<<pgrid, 256, 0, stream>>>(B3, off, epk, B2, N,
                                           stats1, g1, be1, invN);
    hipMemsetAsync(stats2, 0, 2 * NF * sizeof(float), stream);
    mgemm_k<128, 1><<<ggrid, 256, 0, stream>>>(B2, W2b, b2, B1, N, 0, stats2);

    // ---- BN2+ReLU -> out_h (fp32) + hb (bf16, into B2) ----
    bnrelu2_k<<<c4grid, 256, 0, stream>>>(B1, stats2, g2, be2, out_h, B2,
                                          N * NF / 4, invN);

    // ---- logits = propagate(h @ W3^T) + b3 ----
    mgemm_k<64, 1><<<ggrid, 256, 0, stream>>>(B2, W3b, nullptr, B3, N, 0, nullptr);
    gather64_k<<<p8grid, 256, 0, stream>>>(B3, off, epk, b3, out_logits, N);

    // ---- proj MLP fused: z = relu(h@pW1.T+pb1) @ pW2.T + pb2 ----
    projf_k<<<ggrid, 256, 0, stream>>>(B2, pW1b, pb1, pW2b, pb2, out_z, N);
}

// Round 6
// 647.239 us; speedup vs baseline: 1.2315x; 1.0070x over previous
//
#include <hip/hip_runtime.h>

// SGGCN forward, round 10 (= round 9 + 4-stream/16-lane wide gathers):
//  - gather_k: 4 edge-streams per wave (16 lanes x ushort8 = 16B/lane), 4-deep
//    unroll -> 16 edges in flight/wave, half the VMEM instr rate of round 9.
//  - gather64_k: 2 rows/wave, each row = 2 streams x 16 lanes x ushort4.
//  - order-only accumulation-tree reshape (rounds 0/5/9 all landed 0.125).
//  - everything else: round-9 verbatim (CSR bucketed sort, mgemm, bnrelu2,
//    projf fused proj MLP).

#define NF 128

using short8   = __attribute__((ext_vector_type(8))) short;
using ushort8v = __attribute__((ext_vector_type(8))) unsigned short;
using f32x4    = __attribute__((ext_vector_type(4))) float;

__device__ __forceinline__ float b2f(unsigned short u) {
    return __uint_as_float(((unsigned)u) << 16);
}
__device__ __forceinline__ unsigned short f2b(float f) {
    unsigned u = __float_as_uint(f);
    u += 0x7fff + ((u >> 16) & 1);          // RNE
    return (unsigned short)(u >> 16);
}

// ================= CSR build (bucketed) =================
__global__ __launch_bounds__(256) void bhist_k(const int* __restrict__ ei,
                                               int* __restrict__ bhist,
                                               int E, int nbuk)
{
    __shared__ int cnt[512];
    int t = threadIdx.x;
    cnt[t] = 0; cnt[t + 256] = 0;
    __syncthreads();
    int e0 = blockIdx.x * 2048;
    int eend = min(e0 + 2048, E);
    for (int i = e0 + t; i < eend; i += 256)
        atomicAdd(&cnt[ei[E + i] >> 8], 1);
    __syncthreads();
    for (int b = t; b < nbuk; b += 256) {
        int c = cnt[b];
        if (c) atomicAdd(&bhist[b], c);
    }
}

__global__ __launch_bounds__(512) void bscan_k(const int* __restrict__ bhist,
                                               int* __restrict__ bbase,
                                               int* __restrict__ bcur, int nbuk)
{
    __shared__ int sc[512];
    int t = threadIdx.x;
    int v = (t < nbuk) ? bhist[t] : 0;
    sc[t] = v;
    __syncthreads();
    for (int ofs = 1; ofs < 512; ofs <<= 1) {
        int x = (t >= ofs) ? sc[t - ofs] : 0;
        __syncthreads();
        sc[t] += x;
        __syncthreads();
    }
    if (t < nbuk) {
        int ex = sc[t] - v;                 // exclusive
        bbase[t] = ex;
        bcur[t]  = ex;
    }
}

__global__ __launch_bounds__(256) void filla_k(const int* __restrict__ ei,
                                               const float* __restrict__ ew,
                                               int* __restrict__ bcur,
                                               int2* __restrict__ tmp, int E)
{
    __shared__ int dstg[2048];
    __shared__ int cnt[512];
    __shared__ int base[512];
    int t = threadIdx.x;
    cnt[t] = 0; cnt[t + 256] = 0;
    __syncthreads();
    int e0 = blockIdx.x * 2048;
    int eend = min(e0 + 2048, E);
    int n = eend - e0;
    for (int i = t; i < n; i += 256) {
        int d = ei[E + e0 + i];
        dstg[i] = d;
        atomicAdd(&cnt[d >> 8], 1);
    }
    __syncthreads();
    for (int b = t; b < 512; b += 256) {
        int c = cnt[b];
        base[b] = c ? atomicAdd(&bcur[b], c) : 0;  // claim contiguous run
        cnt[b] = 0;
    }
    __syncthreads();
    for (int i = t; i < n; i += 256) {
        int d = dstg[i];
        int b = d >> 8;
        int r = atomicAdd(&cnt[b], 1);             // LDS rank within run
        int2 q;
        q.x = (int)(((unsigned)ei[e0 + i]) | (((unsigned)(d & 255)) << 24));
        q.y = __float_as_int(ew[e0 + i]);
        tmp[base[b] + r] = q;
    }
}

__global__ __launch_bounds__(512) void fillb_k(const int2* __restrict__ tmp,
                                               const int* __restrict__ bbase,
                                               int* __restrict__ off,
                                               int2* __restrict__ epk,
                                               int N, int E, int nbuk)
{
    __shared__ int lcnt[256];
    __shared__ int lcur[256];
    int t = threadIdx.x;
    int b = blockIdx.x;
    int lo = b << 8;
    int nn = min(256, N - lo);
    if (t < 256) lcnt[t] = 0;
    __syncthreads();
    int s = bbase[b];
    int e_end = (b + 1 < nbuk) ? bbase[b + 1] : E;
    for (int i = s + t; i < e_end; i += 512)
        atomicAdd(&lcnt[((unsigned)tmp[i].x) >> 24], 1);
    __syncthreads();
    int v = (t < 256) ? lcnt[t] : 0;
    for (int ofs = 1; ofs < 256; ofs <<= 1) {       // inclusive Hillis-Steele
        int x = (t >= ofs && t < 256) ? lcnt[t - ofs] : 0;
        __syncthreads();
        if (t < 256) lcnt[t] += x;
        __syncthreads();
    }
    if (t < 256) {
        int st = s + lcnt[t] - v;                   // exclusive + bucket base
        lcur[t] = st;
        if (t < nn) off[lo + t] = st;
    }
    if (b == 0 && t == 0) off[N] = E;
    __syncthreads();
    for (int i = s + t; i < e_end; i += 512) {
        int2 q = tmp[i];
        unsigned qx = (unsigned)q.x;
        int pos = atomicAdd(&lcur[qx >> 24], 1);    // LDS cursor
        int2 o;
        o.x = (int)(qx & 0xFFFFFF);
        o.y = q.y;
        epk[pos] = o;
    }
}

// ================= converts =================
__global__ __launch_bounds__(256) void convx_k(const float* __restrict__ x,
                                               unsigned short* __restrict__ xb,
                                               int total4)
{
    int idx = blockIdx.x * 256 + threadIdx.x;
    if (idx >= total4) return;
    float4 v = *(const float4*)&x[(size_t)idx * 4];
    ushort4 o;
    o.x = f2b(v.x); o.y = f2b(v.y); o.z = f2b(v.z); o.w = f2b(v.w);
    *(ushort4*)&xb[(size_t)idx * 4] = o;
}

// W [M][128] fp32 -> frag-ordered bf16: Wb[((nb*4+ks)*64 + lane)*8 + j]
//   = W[nb*16 + (lane&15)][ks*32 + (lane>>4)*8 + j]
__global__ __launch_bounds__(64) void convw_k(const float* __restrict__ W,
                                              unsigned short* __restrict__ Wb)
{
    int lane = threadIdx.x;
    int nb = blockIdx.x >> 2, ks = blockIdx.x & 3;
    const float* src = W + (size_t)(nb * 16 + (lane & 15)) * 128 + ks * 32 + (lane >> 4) * 8;
    unsigned short* dst = Wb + ((size_t)blockIdx.x * 64 + lane) * 8;
#pragma unroll
    for (int j = 0; j < 8; j++) dst[j] = f2b(src[j]);
}

// ====== gather propagate, 4 edge-streams/wave (bf16 in/out, 128 cols) ======
// One row per wave (4 waves/block). half = lane>>4 picks the edge stream
// (0..3), sub = lane&15 covers 8 cols via ushort8 (16B). 4-deep unroll per
// stream -> 16 edges in flight. Streams combined with shfl_xor(16)+(32).
template <int BN>
__global__ __launch_bounds__(256) void gather_k(
    const unsigned short* __restrict__ h, const int* __restrict__ off,
    const int2* __restrict__ epk, unsigned short* __restrict__ p, int N,
    const float* __restrict__ bnstats, const float* __restrict__ g,
    const float* __restrict__ be, float invN)
{
    int row = blockIdx.x * 4 + (threadIdx.x >> 6);
    if (row >= N) return;
    int lane = threadIdx.x & 63;
    int half = lane >> 4;          // edge stream 0..3
    int sub  = lane & 15;
    int c0 = sub * 8;

    float sc[8], sh[8];
#pragma unroll
    for (int j = 0; j < 8; j++) { sc[j] = 1.f; sh[j] = 0.f; }
    if (BN) {
#pragma unroll
        for (int j = 0; j < 8; j++) {
            float m = bnstats[c0 + j] * invN;
            float v = bnstats[NF + c0 + j] * invN - m * m;
            float r = rsqrtf(v + 1e-5f) * g[c0 + j];
            sc[j] = r; sh[j] = be[c0 + j] - m * r;
        }
    }

    int beg = off[row], end = off[row + 1];
    float a[8];
#pragma unroll
    for (int j = 0; j < 8; j++) a[j] = 0.f;

#define PROC_EDGE(qq, uu)                                                     \
    {                                                                         \
        float w = __int_as_float((qq).y);                                     \
        _Pragma("unroll")                                                     \
        for (int j = 0; j < 8; j++) {                                         \
            float v = b2f((unsigned short)(uu)[j]);                           \
            if (BN) v = fmaxf(fmaf(v, sc[j], sh[j]), 0.f);                    \
            a[j] = fmaf(v, w, a[j]);                                          \
        }                                                                     \
    }

    int e = beg;
    for (; e + 16 <= end; e += 16) {
        int2 q0 = epk[e + 0 + half],  q1 = epk[e + 4 + half];
        int2 q2 = epk[e + 8 + half],  q3 = epk[e + 12 + half];
        ushort8v u0 = *(const ushort8v*)&h[(size_t)q0.x * NF + c0];
        ushort8v u1 = *(const ushort8v*)&h[(size_t)q1.x * NF + c0];
        ushort8v u2 = *(const ushort8v*)&h[(size_t)q2.x * NF + c0];
        ushort8v u3 = *(const ushort8v*)&h[(size_t)q3.x * NF + c0];
        PROC_EDGE(q0, u0); PROC_EDGE(q1, u1);
        PROC_EDGE(q2, u2); PROC_EDGE(q3, u3);
    }
    for (; e + 4 <= end; e += 4) {
        int2 q = epk[e + half];
        ushort8v u = *(const ushort8v*)&h[(size_t)q.x * NF + c0];
        PROC_EDGE(q, u);
    }
    if (half < end - e) {                          // tail: 0..3 edges
        int2 q = epk[e + half];
        ushort8v u = *(const ushort8v*)&h[(size_t)q.x * NF + c0];
        PROC_EDGE(q, u);
    }
#undef PROC_EDGE

#pragma unroll
    for (int j = 0; j < 8; j++) {
        a[j] += __shfl_xor(a[j], 16);
        a[j] += __shfl_xor(a[j], 32);
    }

    if (half == 0) {
        ushort8v o;
#pragma unroll
        for (int j = 0; j < 8; j++) o[j] = f2b(a[j]);
        *(ushort8v*)&p[(size_t)row * NF + c0] = o;
    }
}

// ====== gather over 64-dim bf16 rows -> fp32 logits + bias ======
// 2 rows per wave (8 rows/block). Within a 32-lane half: str = bit4, sub =
// lane&15 covers 4 cols via ushort4 (8B). 4-deep unroll -> 8 edges in flight.
__global__ __launch_bounds__(256) void gather64_k(
    const unsigned short* __restrict__ y, const int* __restrict__ off,
    const int2* __restrict__ epk, const float* __restrict__ bias,
    float* __restrict__ out, int N)
{
    int row = blockIdx.x * 8 + (threadIdx.x >> 5);
    if (row >= N) return;
    int l32 = threadIdx.x & 31;
    int str = l32 >> 4;            // edge stream 0..1
    int sub = l32 & 15;
    int c0 = sub * 4;

    int beg = off[row], end = off[row + 1];
    float a[4] = {0.f, 0.f, 0.f, 0.f};

#define PROC_E64(qq, uu)                                                      \
    {                                                                         \
        float w = __int_as_float((qq).y);                                     \
        a[0] = fmaf(b2f((uu).x), w, a[0]);                                    \
        a[1] = fmaf(b2f((uu).y), w, a[1]);                                    \
        a[2] = fmaf(b2f((uu).z), w, a[2]);                                    \
        a[3] = fmaf(b2f((uu).w), w, a[3]);                                    \
    }

    int e = beg;
    for (; e + 8 <= end; e += 8) {
        int2 q0 = epk[e + 0 + str], q1 = epk[e + 2 + str];
        int2 q2 = epk[e + 4 + str], q3 = epk[e + 6 + str];
        ushort4 u0 = *(const ushort4*)&y[(size_t)q0.x * 64 + c0];
        ushort4 u1 = *(const ushort4*)&y[(size_t)q1.x * 64 + c0];
        ushort4 u2 = *(const ushort4*)&y[(size_t)q2.x * 64 + c0];
        ushort4 u3 = *(const ushort4*)&y[(size_t)q3.x * 64 + c0];
        PROC_E64(q0, u0); PROC_E64(q1, u1);
        PROC_E64(q2, u2); PROC_E64(q3, u3);
    }
    for (; e + 2 <= end; e += 2) {
        int2 q = epk[e + str];
        ushort4 u = *(const ushort4*)&y[(size_t)q.x * 64 + c0];
        PROC_E64(q, u);
    }
    if (str == 0 && e < end) {
        int2 q = epk[e];
        ushort4 u = *(const ushort4*)&y[(size_t)q.x * 64 + c0];
        PROC_E64(q, u);
    }
#undef PROC_E64

#pragma unroll
    for (int j = 0; j < 4; j++) a[j] += __shfl_xor(a[j], 16);

    if (str == 0) {
        float4 o;
        o.x = a[0] + bias[c0];     o.y = a[1] + bias[c0 + 1];
        o.z = a[2] + bias[c0 + 2]; o.w = a[3] + bias[c0 + 3];
        *(float4*)&out[(size_t)row * 64 + c0] = o;
    }
}

// ================= MFMA GEMM: C[N,M] = A[N,128]bf16 @ W[M,128]^T + b ==========
// (round-5 verbatim)
template <int M, int COUT>
__global__ __launch_bounds__(256) void mgemm_k(
    const unsigned short* __restrict__ A, const unsigned short* __restrict__ Wb,
    const float* __restrict__ bias, void* __restrict__ Cp,
    int N, int relu, float* __restrict__ stats)
{
    constexpr int MI = (M == 128) ? 4 : 2;
    __shared__ float sbuf[256];

    const int tid = threadIdx.x, wid = tid >> 6, lane = tid & 63;
    const int quad = lane >> 4, l16 = lane & 15;
    const int rowBase = blockIdx.x * 128;
    int r0, c0;
    if constexpr (M == 128) { r0 = (wid >> 1) * 64; c0 = (wid & 1) * 64; }
    else                    { r0 = wid * 32;        c0 = 0; }

    f32x4 acc[MI][4];
#pragma unroll
    for (int mi = 0; mi < MI; mi++)
#pragma unroll
        for (int ni = 0; ni < 4; ni++)
#pragma unroll
            for (int r = 0; r < 4; r++) acc[mi][ni][r] = 0.f;

#pragma unroll
    for (int ks = 0; ks < 4; ++ks) {
        short8 af[MI], bf[4];
#pragma unroll
        for (int mi = 0; mi < MI; mi++) {
            int gr = rowBase + r0 + mi * 16 + l16;
            gr = (gr < N) ? gr : (N - 1);
            af[mi] = *(const short8*)(A + (size_t)gr * 128 + ks * 32 + quad * 8);
        }
#pragma unroll
        for (int ni = 0; ni < 4; ni++) {
            int nb = (c0 >> 4) + ni;
            bf[ni] = *(const short8*)(Wb + ((size_t)(nb * 4 + ks) * 64 + lane) * 8);
        }
#pragma unroll
        for (int mi = 0; mi < MI; mi++)
#pragma unroll
            for (int ni = 0; ni < 4; ni++)
                acc[mi][ni] = __builtin_amdgcn_mfma_f32_16x16x32_bf16(
                    af[mi], bf[ni], acc[mi][ni], 0, 0, 0);
    }

    float csum[4] = {0.f, 0.f, 0.f, 0.f}, csq[4] = {0.f, 0.f, 0.f, 0.f};
#pragma unroll
    for (int mi = 0; mi < MI; mi++) {
#pragma unroll
        for (int r = 0; r < 4; r++) {
            int gr = rowBase + r0 + mi * 16 + quad * 4 + r;
            if (gr >= N) continue;
#pragma unroll
            for (int ni = 0; ni < 4; ni++) {
                int col = c0 + ni * 16 + l16;
                float v = acc[mi][ni][r] + (bias ? bias[col] : 0.f);
                if (relu) v = fmaxf(v, 0.f);
                if constexpr (COUT == 1)
                    ((unsigned short*)Cp)[(size_t)gr * M + col] = f2b(v);
                else
                    ((float*)Cp)[(size_t)gr * M + col] = v;
                csum[ni] += v;
                csq[ni]  += v * v;
            }
        }
    }

    if (stats) {
        sbuf[tid] = 0.f;
        __syncthreads();
#pragma unroll
        for (int ni = 0; ni < 4; ni++) {
            int col = c0 + ni * 16 + l16;
            atomicAdd(&sbuf[col], csum[ni]);
            atomicAdd(&sbuf[128 + col], csq[ni]);
        }
        __syncthreads();
        if (tid < 128) {
            unsafeAtomicAdd(&stats[tid], sbuf[tid]);
            unsafeAtomicAdd(&stats[NF + tid], sbuf[128 + tid]);
        }
    }
}

// ======= BN2 + affine + ReLU: bf16 pre -> fp32 out_h AND bf16 hb ==========
// (round-5 verbatim)
__global__ __launch_bounds__(256) void bnrelu2_k(
    const unsigned short* __restrict__ pre, const float* __restrict__ stats,
    const float* __restrict__ g, const float* __restrict__ be,
    float* __restrict__ outh, unsigned short* __restrict__ hb,
    int total4, float invN)
{
    int idx = blockIdx.x * 256 + threadIdx.x;
    if (idx >= total4) return;
    int c = (idx * 4) & 127;
    ushort4 u = *(const ushort4*)&pre[(size_t)idx * 4];
    float in[4] = {b2f(u.x), b2f(u.y), b2f(u.z), b2f(u.w)};
    float o[4];
#pragma unroll
    for (int i = 0; i < 4; i++) {
        float m   = stats[c + i] * invN;
        float var = stats[NF + c + i] * invN - m * m;
        float rs  = rsqrtf(var + 1e-5f);
        o[i] = fmaxf((in[i] - m) * rs * g[c + i] + be[c + i], 0.f);
    }
    float4 f; f.x = o[0]; f.y = o[1]; f.z = o[2]; f.w = o[3];
    *(float4*)&outh[(size_t)idx * 4] = f;
    ushort4 h4;
    h4.x = f2b(o[0]); h4.y = f2b(o[1]); h4.z = f2b(o[2]); h4.w = f2b(o[3]);
    *(ushort4*)&hb[(size_t)idx * 4] = h4;
}

// ====== fused proj MLP: Z = relu(A@W1^T + b1) @ W2^T + b2, LDS intermediate ====
__global__ __launch_bounds__(256) void projf_k(
    const unsigned short* __restrict__ A, const unsigned short* __restrict__ W1b,
    const float* __restrict__ bias1, const unsigned short* __restrict__ W2b,
    const float* __restrict__ bias2, float* __restrict__ Z, int N)
{
    __shared__ unsigned short tbuf[128][136];

    const int tid = threadIdx.x, wid = tid >> 6, lane = tid & 63;
    const int quad = lane >> 4, l16 = lane & 15;
    const int rowBase = blockIdx.x * 128;
    const int r0 = (wid >> 1) * 64, c0 = (wid & 1) * 64;

    f32x4 acc[4][4];
#pragma unroll
    for (int mi = 0; mi < 4; mi++)
#pragma unroll
        for (int ni = 0; ni < 4; ni++)
#pragma unroll
            for (int r = 0; r < 4; r++) acc[mi][ni][r] = 0.f;

    // stage 1: relu(A@W1^T + b1) -> LDS (bf16)
#pragma unroll
    for (int ks = 0; ks < 4; ++ks) {
        short8 af[4], bf[4];
#pragma unroll
        for (int mi = 0; mi < 4; mi++) {
            int gr = rowBase + r0 + mi * 16 + l16;
            gr = (gr < N) ? gr : (N - 1);
            af[mi] = *(const short8*)(A + (size_t)gr * 128 + ks * 32 + quad * 8);
        }
#pragma unroll
        for (int ni = 0; ni < 4; ni++) {
            int nb = (c0 >> 4) + ni;
            bf[ni] = *(const short8*)(W1b + ((size_t)(nb * 4 + ks) * 64 + lane) * 8);
        }
#pragma unroll
        for (int mi = 0; mi < 4; mi++)
#pragma unroll
            for (int ni = 0; ni < 4; ni++)
                acc[mi][ni] = __builtin_amdgcn_mfma_f32_16x16x32_bf16(
                    af[mi], bf[ni], acc[mi][ni], 0, 0, 0);
    }
#pragma unroll
    for (int mi = 0; mi < 4; mi++)
#pragma unroll
        for (int r = 0; r < 4; r++) {
            int lr = r0 + mi * 16 + quad * 4 + r;
#pragma unroll
            for (int ni = 0; ni < 4; ni++) {
                int col = c0 + ni * 16 + l16;
                float v = fmaxf(acc[mi][ni][r] + bias1[col], 0.f);
                tbuf[lr][col] = f2b(v);
            }
        }
    __syncthreads();

    // stage 2: T@W2^T + b2 -> Z (fp32), A-frags from LDS
#pragma unroll
    for (int mi = 0; mi < 4; mi++)
#pragma unroll
        for (int ni = 0; ni < 4; ni++)
#pragma unroll
            for (int r = 0; r < 4; r++) acc[mi][ni][r] = 0.f;

#pragma unroll
    for (int ks = 0; ks < 4; ++ks) {
        short8 af[4], bf[4];
#pragma unroll
        for (int mi = 0; mi < 4; mi++)
            af[mi] = *(const short8*)&tbuf[r0 + mi * 16 + l16][ks * 32 + quad * 8];
#pragma unroll
        for (int ni = 0; ni < 4; ni++) {
            int nb = (c0 >> 4) + ni;
            bf[ni] = *(const short8*)(W2b + ((size_t)(nb * 4 + ks) * 64 + lane) * 8);
        }
#pragma unroll
        for (int mi = 0; mi < 4; mi++)
#pragma unroll
            for (int ni = 0; ni < 4; ni++)
                acc[mi][ni] = __builtin_amdgcn_mfma_f32_16x16x32_bf16(
                    af[mi], bf[ni], acc[mi][ni], 0, 0, 0);
    }
#pragma unroll
    for (int mi = 0; mi < 4; mi++)
#pragma unroll
        for (int r = 0; r < 4; r++) {
            int gr = rowBase + r0 + mi * 16 + quad * 4 + r;
            if (gr >= N) continue;
#pragma unroll
            for (int ni = 0; ni < 4; ni++) {
                int col = c0 + ni * 16 + l16;
                Z[(size_t)gr * 128 + col] = acc[mi][ni][r] + bias2[col];
            }
        }
}

extern "C" void kernel_launch(void* const* d_in, const int* in_sizes, int n_in,
                              void* d_out, int out_size, void* d_ws, size_t ws_size,
                              hipStream_t stream)
{
    const float* x   = (const float*)d_in[0];
    const int*   ei  = (const int*)d_in[1];
    const float* ew  = (const float*)d_in[2];
    const float* W1  = (const float*)d_in[3];
    const float* b1  = (const float*)d_in[4];
    const float* W2  = (const float*)d_in[5];
    const float* b2  = (const float*)d_in[6];
    const float* W3  = (const float*)d_in[7];
    const float* b3  = (const float*)d_in[8];
    const float* g1  = (const float*)d_in[9];
    const float* be1 = (const float*)d_in[10];
    const float* g2  = (const float*)d_in[11];
    const float* be2 = (const float*)d_in[12];
    const float* pW1 = (const float*)d_in[13];
    const float* pb1 = (const float*)d_in[14];
    const float* pW2 = (const float*)d_in[15];
    const float* pb2 = (const float*)d_in[16];

    const int N = in_sizes[0] / NF;
    const int E = in_sizes[2];

    float* out_logits = (float*)d_out;
    float* out_h      = out_logits + (size_t)N * 64;
    float* out_z      = out_h + (size_t)N * NF;

    // ---- workspace layout (round-5) ----
    const size_t rowsUS = (size_t)N * NF;
    int2*           epk = (int2*)d_ws;                           // E*8 B
    unsigned short* B1  = (unsigned short*)(epk + E);            // xb -> pre2b
    unsigned short* B2  = B1 + rowsUS;                           // tmp -> p0/p1 -> hb
    unsigned short* B3  = B2 + rowsUS;                           // pre1 -> y -> t
    float* stats1 = (float*)(B3 + rowsUS);                       // 256
    float* stats2 = stats1 + 256;                                // 256
    float* wconv  = stats2 + 256;
    unsigned short* W1b  = (unsigned short*)wconv;               // 128*128
    unsigned short* W2b  = W1b + 128 * 128;
    unsigned short* pW1b = W2b + 128 * 128;
    unsigned short* pW2b = pW1b + 128 * 128;
    unsigned short* W3b  = pW2b + 128 * 128;                     // 64*128
    int* off   = (int*)(W3b + 64 * 128);                         // N+1
    int* bhist = off + N + 1;                                    // 512
    int* bbase = bhist + 512;                                    // 512
    int* bcur  = bbase + 512;                                    // 512
    int2* tmp  = (int2*)B2;   // bucket-sorted intermediate; dead before the
                              // first gather writes B2 (serial stream)

    const int nbuk   = (N + 255) >> 8;
    const int ggrid  = (N + 127) / 128;
    const int pgrid  = (N + 3) / 4;
    const int p8grid = (N + 7) / 8;
    const int c4grid = (N * NF / 4 + 255) / 256;
    const int egrid  = (E + 2047) / 2048;
    const float invN = 1.f / (float)N;

    // ---- converts ----
    convx_k<<<c4grid, 256, 0, stream>>>(x, B1, N * NF / 4);
    convw_k<<<32, 64, 0, stream>>>(W1, W1b);
    convw_k<<<32, 64, 0, stream>>>(W2, W2b);
    convw_k<<<32, 64, 0, stream>>>(pW1, pW1b);
    convw_k<<<32, 64, 0, stream>>>(pW2, pW2b);
    convw_k<<<16, 64, 0, stream>>>(W3, W3b);

    // ---- CSR build (bucketed counting sort) ----
    hipMemsetAsync(bhist, 0, 512 * sizeof(int), stream);
    bhist_k<<<egrid, 256, 0, stream>>>(ei, bhist, E, nbuk);
    bscan_k<<<1, 512, 0, stream>>>(bhist, bbase, bcur, nbuk);
    filla_k<<<egrid, 256, 0, stream>>>(ei, ew, bcur, tmp, E);
    fillb_k<<<nbuk, 512, 0, stream>>>(tmp, bbase, off, epk, N, E, nbuk);

    // ---- layer 1 ----
    gather_k<0><<<pgrid, 256, 0, stream>>>(B1, off, epk, B2, N,
                                           nullptr, nullptr, nullptr, 0.f);
    hipMemsetAsync(stats1, 0, 2 * NF * sizeof(float), stream);
    mgemm_k<128, 1><<<ggrid, 256, 0, stream>>>(B2, W1b, b1, B3, N, 0, stats1);

    // ---- layer 2 (BN1+ReLU fused into gather load) ----
    gather_k<1><<<pgrid, 256, 0, stream>>>(B3, off, epk, B2, N,
                                           stats1, g1, be1, invN);
    hipMemsetAsync(stats2, 0, 2 * NF * sizeof(float), stream);
    mgemm_k<128, 1><<<ggrid, 256, 0, stream>>>(B2, W2b, b2, B1, N, 0, stats2);

    // ---- BN2+ReLU -> out_h (fp32) + hb (bf16, into B2) ----
    bnrelu2_k<<<c4grid, 256, 0, stream>>>(B1, stats2, g2, be2, out_h, B2,
                                          N * NF / 4, invN);

    // ---- logits = propagate(h @ W3^T) + b3 ----
    mgemm_k<64, 1><<<ggrid, 256, 0, stream>>>(B2, W3b, nullptr, B3, N, 0, nullptr);
    gather64_k<<<p8grid, 256, 0, stream>>>(B3, off, epk, b3, out_logits, N);

    // ---- proj MLP fused: z = relu(h@pW1.T+pb1) @ pW2.T + pb2 ----
    projf_k<<<ggrid, 256, 0, stream>>>(B2, pW1b, pb1, pW2b, pb2, out_z, N);
}

// Round 7
// 589.310 us; speedup vs baseline: 1.3525x; 1.0983x over previous
//
#include <hip/hip_runtime.h>

// SGGCN forward, round 11 (= round 10 + CSR/launch-overhead trims):
//  - bhist_k ELIMINATED: fixed-capacity bucket regions (CAP=6144 per 256-node
//    bucket, mean fill 4092, +32 sigma headroom). filla2_k claims runs straight
//    off zeroed bcur; bscan scans the final counts.
//  - filla2_k: 4096 edges/block (was 2048) -> longer runs, fewer claims.
//  - convw x6 -> one convw_all_k launch. 3 memsets -> 1 (stats1|stats2|bcur).
//  - gather64_k: 1 row/wave, 4 edge-streams x 16 lanes (mirrors gather_k).
//  - gather_k / mgemm / bnrelu2 / projf: round-10 verbatim (passed, 0.125).

#define NF 128
#define BCAP 6144

using short8   = __attribute__((ext_vector_type(8))) short;
using ushort8v = __attribute__((ext_vector_type(8))) unsigned short;
using f32x4    = __attribute__((ext_vector_type(4))) float;

__device__ __forceinline__ float b2f(unsigned short u) {
    return __uint_as_float(((unsigned)u) << 16);
}
__device__ __forceinline__ unsigned short f2b(float f) {
    unsigned u = __float_as_uint(f);
    u += 0x7fff + ((u >> 16) & 1);          // RNE
    return (unsigned short)(u >> 16);
}

// ================= CSR build (bucketed, fixed-capacity) =================
// bucket b = dst >> 8. tmp record: x = src | (dst&255)<<24, y = weight bits.
// tmp region for bucket b is [b*BCAP, b*BCAP + count[b]).

__global__ __launch_bounds__(512) void filla2_k(const int* __restrict__ ei,
                                                const float* __restrict__ ew,
                                                int* __restrict__ bcur,
                                                int2* __restrict__ tmp, int E)
{
    __shared__ int dstg[4096];
    __shared__ int cnt[512];
    __shared__ int base[512];
    int t = threadIdx.x;
    cnt[t] = 0;
    __syncthreads();
    int e0 = blockIdx.x * 4096;
    int eend = min(e0 + 4096, E);
    int n = eend - e0;
    for (int i = t; i < n; i += 512) {
        int d = ei[E + e0 + i];
        dstg[i] = d;
        atomicAdd(&cnt[d >> 8], 1);
    }
    __syncthreads();
    {
        int c = cnt[t];
        base[t] = c ? (t * BCAP + atomicAdd(&bcur[t], c)) : 0;  // claim run
        cnt[t] = 0;
    }
    __syncthreads();
    for (int i = t; i < n; i += 512) {
        int d = dstg[i];
        int b = d >> 8;
        int r = atomicAdd(&cnt[b], 1);             // LDS rank within run
        int2 q;
        q.x = (int)(((unsigned)ei[e0 + i]) | (((unsigned)(d & 255)) << 24));
        q.y = __float_as_int(ew[e0 + i]);
        tmp[base[b] + r] = q;
    }
}

// exclusive prefix over bucket counts -> bbase (compaction bases for off/epk)
__global__ __launch_bounds__(512) void bscan_k(const int* __restrict__ bcnt,
                                               int* __restrict__ bbase, int nbuk)
{
    __shared__ int sc[512];
    int t = threadIdx.x;
    int v = (t < nbuk) ? bcnt[t] : 0;
    sc[t] = v;
    __syncthreads();
    for (int ofs = 1; ofs < 512; ofs <<= 1) {
        int x = (t >= ofs) ? sc[t - ofs] : 0;
        __syncthreads();
        sc[t] += x;
        __syncthreads();
    }
    if (t < nbuk) bbase[t] = sc[t] - v;            // exclusive
}

__global__ __launch_bounds__(512) void fillb_k(const int2* __restrict__ tmp,
                                               const int* __restrict__ bbase,
                                               const int* __restrict__ bcnt,
                                               int* __restrict__ off,
                                               int2* __restrict__ epk,
                                               int N, int E, int nbuk)
{
    __shared__ int lcnt[256];
    __shared__ int lcur[256];
    int t = threadIdx.x;
    int b = blockIdx.x;
    int lo = b << 8;
    int nn = min(256, N - lo);
    if (t < 256) lcnt[t] = 0;
    __syncthreads();
    const int2* src = tmp + (size_t)b * BCAP;
    int cntb = bcnt[b];
    int s = bbase[b];
    for (int i = t; i < cntb; i += 512)
        atomicAdd(&lcnt[((unsigned)src[i].x) >> 24], 1);
    __syncthreads();
    int v = (t < 256) ? lcnt[t] : 0;
    for (int ofs = 1; ofs < 256; ofs <<= 1) {       // inclusive Hillis-Steele
        int x = (t >= ofs && t < 256) ? lcnt[t - ofs] : 0;
        __syncthreads();
        if (t < 256) lcnt[t] += x;
        __syncthreads();
    }
    if (t < 256) {
        int st = s + lcnt[t] - v;                   // exclusive + bucket base
        lcur[t] = st;
        if (t < nn) off[lo + t] = st;
    }
    if (b == 0 && t == 0) off[N] = E;
    __syncthreads();
    for (int i = t; i < cntb; i += 512) {
        int2 q = src[i];
        unsigned qx = (unsigned)q.x;
        int pos = atomicAdd(&lcur[qx >> 24], 1);    // LDS cursor
        int2 o;
        o.x = (int)(qx & 0xFFFFFF);
        o.y = q.y;
        epk[pos] = o;
    }
}

// ================= converts =================
__global__ __launch_bounds__(256) void convx_k(const float* __restrict__ x,
                                               unsigned short* __restrict__ xb,
                                               int total4)
{
    int idx = blockIdx.x * 256 + threadIdx.x;
    if (idx >= total4) return;
    float4 v = *(const float4*)&x[(size_t)idx * 4];
    ushort4 o;
    o.x = f2b(v.x); o.y = f2b(v.y); o.z = f2b(v.z); o.w = f2b(v.w);
    *(ushort4*)&xb[(size_t)idx * 4] = o;
}

// all 5 weight converts in one launch. W [M][128] fp32 -> frag-ordered bf16:
//   Wb[((nb*4+ks)*64 + lane)*8 + j] = W[nb*16+(lane&15)][ks*32+(lane>>4)*8+j]
__global__ __launch_bounds__(64) void convw_all_k(
    const float* __restrict__ W1,  const float* __restrict__ W2,
    const float* __restrict__ pW1, const float* __restrict__ pW2,
    const float* __restrict__ W3,
    unsigned short* __restrict__ W1b,  unsigned short* __restrict__ W2b,
    unsigned short* __restrict__ pW1b, unsigned short* __restrict__ pW2b,
    unsigned short* __restrict__ W3b)
{
    int bid = blockIdx.x;                          // 0..175
    const float* W; unsigned short* Wb; int lb;
    if      (bid < 32)  { W = W1;  Wb = W1b;  lb = bid; }
    else if (bid < 64)  { W = W2;  Wb = W2b;  lb = bid - 32; }
    else if (bid < 96)  { W = pW1; Wb = pW1b; lb = bid - 64; }
    else if (bid < 128) { W = pW2; Wb = pW2b; lb = bid - 96; }
    else                { W = W3;  Wb = W3b;  lb = bid - 128; }
    int lane = threadIdx.x;
    int nb = lb >> 2, ks = lb & 3;
    const float* src = W + (size_t)(nb * 16 + (lane & 15)) * 128 + ks * 32 + (lane >> 4) * 8;
    unsigned short* dst = Wb + ((size_t)lb * 64 + lane) * 8;
#pragma unroll
    for (int j = 0; j < 8; j++) dst[j] = f2b(src[j]);
}

// ====== gather propagate, 4 edge-streams/wave (bf16 in/out, 128 cols) ======
// (round-10 verbatim)
template <int BN>
__global__ __launch_bounds__(256) void gather_k(
    const unsigned short* __restrict__ h, const int* __restrict__ off,
    const int2* __restrict__ epk, unsigned short* __restrict__ p, int N,
    const float* __restrict__ bnstats, const float* __restrict__ g,
    const float* __restrict__ be, float invN)
{
    int row = blockIdx.x * 4 + (threadIdx.x >> 6);
    if (row >= N) return;
    int lane = threadIdx.x & 63;
    int half = lane >> 4;          // edge stream 0..3
    int sub  = lane & 15;
    int c0 = sub * 8;

    float sc[8], sh[8];
#pragma unroll
    for (int j = 0; j < 8; j++) { sc[j] = 1.f; sh[j] = 0.f; }
    if (BN) {
#pragma unroll
        for (int j = 0; j < 8; j++) {
            float m = bnstats[c0 + j] * invN;
            float v = bnstats[NF + c0 + j] * invN - m * m;
            float r = rsqrtf(v + 1e-5f) * g[c0 + j];
            sc[j] = r; sh[j] = be[c0 + j] - m * r;
        }
    }

    int beg = off[row], end = off[row + 1];
    float a[8];
#pragma unroll
    for (int j = 0; j < 8; j++) a[j] = 0.f;

#define PROC_EDGE(qq, uu)                                                     \
    {                                                                         \
        float w = __int_as_float((qq).y);                                     \
        _Pragma("unroll")                                                     \
        for (int j = 0; j < 8; j++) {                                         \
            float v = b2f((unsigned short)(uu)[j]);                           \
            if (BN) v = fmaxf(fmaf(v, sc[j], sh[j]), 0.f);                    \
            a[j] = fmaf(v, w, a[j]);                                          \
        }                                                                     \
    }

    int e = beg;
    for (; e + 16 <= end; e += 16) {
        int2 q0 = epk[e + 0 + half],  q1 = epk[e + 4 + half];
        int2 q2 = epk[e + 8 + half],  q3 = epk[e + 12 + half];
        ushort8v u0 = *(const ushort8v*)&h[(size_t)q0.x * NF + c0];
        ushort8v u1 = *(const ushort8v*)&h[(size_t)q1.x * NF + c0];
        ushort8v u2 = *(const ushort8v*)&h[(size_t)q2.x * NF + c0];
        ushort8v u3 = *(const ushort8v*)&h[(size_t)q3.x * NF + c0];
        PROC_EDGE(q0, u0); PROC_EDGE(q1, u1);
        PROC_EDGE(q2, u2); PROC_EDGE(q3, u3);
    }
    for (; e + 4 <= end; e += 4) {
        int2 q = epk[e + half];
        ushort8v u = *(const ushort8v*)&h[(size_t)q.x * NF + c0];
        PROC_EDGE(q, u);
    }
    if (half < end - e) {                          // tail: 0..3 edges
        int2 q = epk[e + half];
        ushort8v u = *(const ushort8v*)&h[(size_t)q.x * NF + c0];
        PROC_EDGE(q, u);
    }
#undef PROC_EDGE

#pragma unroll
    for (int j = 0; j < 8; j++) {
        a[j] += __shfl_xor(a[j], 16);
        a[j] += __shfl_xor(a[j], 32);
    }

    if (half == 0) {
        ushort8v o;
#pragma unroll
        for (int j = 0; j < 8; j++) o[j] = f2b(a[j]);
        *(ushort8v*)&p[(size_t)row * NF + c0] = o;
    }
}

// ====== gather over 64-dim bf16 rows -> fp32 logits + bias ======
// 1 row/wave, 4 edge-streams x 16 lanes x ushort4 -> 16 edges in flight.
__global__ __launch_bounds__(256) void gather64_k(
    const unsigned short* __restrict__ y, const int* __restrict__ off,
    const int2* __restrict__ epk, const float* __restrict__ bias,
    float* __restrict__ out, int N)
{
    int row = blockIdx.x * 4 + (threadIdx.x >> 6);
    if (row >= N) return;
    int lane = threadIdx.x & 63;
    int str = lane >> 4;           // edge stream 0..3
    int sub = lane & 15;
    int c0 = sub * 4;

    int beg = off[row], end = off[row + 1];
    float a[4] = {0.f, 0.f, 0.f, 0.f};

#define PROC_E64(qq, uu)                                                      \
    {                                                                         \
        float w = __int_as_float((qq).y);                                     \
        a[0] = fmaf(b2f((uu).x), w, a[0]);                                    \
        a[1] = fmaf(b2f((uu).y), w, a[1]);                                    \
        a[2] = fmaf(b2f((uu).z), w, a[2]);                                    \
        a[3] = fmaf(b2f((uu).w), w, a[3]);                                    \
    }

    int e = beg;
    for (; e + 16 <= end; e += 16) {
        int2 q0 = epk[e + 0 + str],  q1 = epk[e + 4 + str];
        int2 q2 = epk[e + 8 + str],  q3 = epk[e + 12 + str];
        ushort4 u0 = *(const ushort4*)&y[(size_t)q0.x * 64 + c0];
        ushort4 u1 = *(const ushort4*)&y[(size_t)q1.x * 64 + c0];
        ushort4 u2 = *(const ushort4*)&y[(size_t)q2.x * 64 + c0];
        ushort4 u3 = *(const ushort4*)&y[(size_t)q3.x * 64 + c0];
        PROC_E64(q0, u0); PROC_E64(q1, u1);
        PROC_E64(q2, u2); PROC_E64(q3, u3);
    }
    for (; e + 4 <= end; e += 4) {
        int2 q = epk[e + str];
        ushort4 u = *(const ushort4*)&y[(size_t)q.x * 64 + c0];
        PROC_E64(q, u);
    }
    if (str < end - e) {                           // tail: 0..3 edges
        int2 q = epk[e + str];
        ushort4 u = *(const ushort4*)&y[(size_t)q.x * 64 + c0];
        PROC_E64(q, u);
    }
#undef PROC_E64

#pragma unroll
    for (int j = 0; j < 4; j++) {
        a[j] += __shfl_xor(a[j], 16);
        a[j] += __shfl_xor(a[j], 32);
    }

    if (lane < 16) {
        float4 o;
        o.x = a[0] + bias[c0];     o.y = a[1] + bias[c0 + 1];
        o.z = a[2] + bias[c0 + 2]; o.w = a[3] + bias[c0 + 3];
        *(float4*)&out[(size_t)row * 64 + c0] = o;
    }
}

// ================= MFMA GEMM: C[N,M] = A[N,128]bf16 @ W[M,128]^T + b ==========
template <int M, int COUT>
__global__ __launch_bounds__(256) void mgemm_k(
    const unsigned short* __restrict__ A, const unsigned short* __restrict__ Wb,
    const float* __restrict__ bias, void* __restrict__ Cp,
    int N, int relu, float* __restrict__ stats)
{
    constexpr int MI = (M == 128) ? 4 : 2;
    __shared__ float sbuf[256];

    const int tid = threadIdx.x, wid = tid >> 6, lane = tid & 63;
    const int quad = lane >> 4, l16 = lane & 15;
    const int rowBase = blockIdx.x * 128;
    int r0, c0;
    if constexpr (M == 128) { r0 = (wid >> 1) * 64; c0 = (wid & 1) * 64; }
    else                    { r0 = wid * 32;        c0 = 0; }

    f32x4 acc[MI][4];
#pragma unroll
    for (int mi = 0; mi < MI; mi++)
#pragma unroll
        for (int ni = 0; ni < 4; ni++)
#pragma unroll
            for (int r = 0; r < 4; r++) acc[mi][ni][r] = 0.f;

#pragma unroll
    for (int ks = 0; ks < 4; ++ks) {
        short8 af[MI], bf[4];
#pragma unroll
        for (int mi = 0; mi < MI; mi++) {
            int gr = rowBase + r0 + mi * 16 + l16;
            gr = (gr < N) ? gr : (N - 1);
            af[mi] = *(const short8*)(A + (size_t)gr * 128 + ks * 32 + quad * 8);
        }
#pragma unroll
        for (int ni = 0; ni < 4; ni++) {
            int nb = (c0 >> 4) + ni;
            bf[ni] = *(const short8*)(Wb + ((size_t)(nb * 4 + ks) * 64 + lane) * 8);
        }
#pragma unroll
        for (int mi = 0; mi < MI; mi++)
#pragma unroll
            for (int ni = 0; ni < 4; ni++)
                acc[mi][ni] = __builtin_amdgcn_mfma_f32_16x16x32_bf16(
                    af[mi], bf[ni], acc[mi][ni], 0, 0, 0);
    }

    float csum[4] = {0.f, 0.f, 0.f, 0.f}, csq[4] = {0.f, 0.f, 0.f, 0.f};
#pragma unroll
    for (int mi = 0; mi < MI; mi++) {
#pragma unroll
        for (int r = 0; r < 4; r++) {
            int gr = rowBase + r0 + mi * 16 + quad * 4 + r;
            if (gr >= N) continue;
#pragma unroll
            for (int ni = 0; ni < 4; ni++) {
                int col = c0 + ni * 16 + l16;
                float v = acc[mi][ni][r] + (bias ? bias[col] : 0.f);
                if (relu) v = fmaxf(v, 0.f);
                if constexpr (COUT == 1)
                    ((unsigned short*)Cp)[(size_t)gr * M + col] = f2b(v);
                else
                    ((float*)Cp)[(size_t)gr * M + col] = v;
                csum[ni] += v;
                csq[ni]  += v * v;
            }
        }
    }

    if (stats) {
        sbuf[tid] = 0.f;
        __syncthreads();
#pragma unroll
        for (int ni = 0; ni < 4; ni++) {
            int col = c0 + ni * 16 + l16;
            atomicAdd(&sbuf[col], csum[ni]);
            atomicAdd(&sbuf[128 + col], csq[ni]);
        }
        __syncthreads();
        if (tid < 128) {
            unsafeAtomicAdd(&stats[tid], sbuf[tid]);
            unsafeAtomicAdd(&stats[NF + tid], sbuf[128 + tid]);
        }
    }
}

// ======= BN2 + affine + ReLU: bf16 pre -> fp32 out_h AND bf16 hb ==========
__global__ __launch_bounds__(256) void bnrelu2_k(
    const unsigned short* __restrict__ pre, const float* __restrict__ stats,
    const float* __restrict__ g, const float* __restrict__ be,
    float* __restrict__ outh, unsigned short* __restrict__ hb,
    int total4, float invN)
{
    int idx = blockIdx.x * 256 + threadIdx.x;
    if (idx >= total4) return;
    int c = (idx * 4) & 127;
    ushort4 u = *(const ushort4*)&pre[(size_t)idx * 4];
    float in[4] = {b2f(u.x), b2f(u.y), b2f(u.z), b2f(u.w)};
    float o[4];
#pragma unroll
    for (int i = 0; i < 4; i++) {
        float m   = stats[c + i] * invN;
        float var = stats[NF + c + i] * invN - m * m;
        float rs  = rsqrtf(var + 1e-5f);
        o[i] = fmaxf((in[i] - m) * rs * g[c + i] + be[c + i], 0.f);
    }
    float4 f; f.x = o[0]; f.y = o[1]; f.z = o[2]; f.w = o[3];
    *(float4*)&outh[(size_t)idx * 4] = f;
    ushort4 h4;
    h4.x = f2b(o[0]); h4.y = f2b(o[1]); h4.z = f2b(o[2]); h4.w = f2b(o[3]);
    *(ushort4*)&hb[(size_t)idx * 4] = h4;
}

// ====== fused proj MLP: Z = relu(A@W1^T + b1) @ W2^T + b2, LDS intermediate ====
__global__ __launch_bounds__(256) void projf_k(
    const unsigned short* __restrict__ A, const unsigned short* __restrict__ W1b,
    const float* __restrict__ bias1, const unsigned short* __restrict__ W2b,
    const float* __restrict__ bias2, float* __restrict__ Z, int N)
{
    __shared__ unsigned short tbuf[128][136];

    const int tid = threadIdx.x, wid = tid >> 6, lane = tid & 63;
    const int quad = lane >> 4, l16 = lane & 15;
    const int rowBase = blockIdx.x * 128;
    const int r0 = (wid >> 1) * 64, c0 = (wid & 1) * 64;

    f32x4 acc[4][4];
#pragma unroll
    for (int mi = 0; mi < 4; mi++)
#pragma unroll
        for (int ni = 0; ni < 4; ni++)
#pragma unroll
            for (int r = 0; r < 4; r++) acc[mi][ni][r] = 0.f;

    // stage 1: relu(A@W1^T + b1) -> LDS (bf16)
#pragma unroll
    for (int ks = 0; ks < 4; ++ks) {
        short8 af[4], bf[4];
#pragma unroll
        for (int mi = 0; mi < 4; mi++) {
            int gr = rowBase + r0 + mi * 16 + l16;
            gr = (gr < N) ? gr : (N - 1);
            af[mi] = *(const short8*)(A + (size_t)gr * 128 + ks * 32 + quad * 8);
        }
#pragma unroll
        for (int ni = 0; ni < 4; ni++) {
            int nb = (c0 >> 4) + ni;
            bf[ni] = *(const short8*)(W1b + ((size_t)(nb * 4 + ks) * 64 + lane) * 8);
        }
#pragma unroll
        for (int mi = 0; mi < 4; mi++)
#pragma unroll
            for (int ni = 0; ni < 4; ni++)
                acc[mi][ni] = __builtin_amdgcn_mfma_f32_16x16x32_bf16(
                    af[mi], bf[ni], acc[mi][ni], 0, 0, 0);
    }
#pragma unroll
    for (int mi = 0; mi < 4; mi++)
#pragma unroll
        for (int r = 0; r < 4; r++) {
            int lr = r0 + mi * 16 + quad * 4 + r;
#pragma unroll
            for (int ni = 0; ni < 4; ni++) {
                int col = c0 + ni * 16 + l16;
                float v = fmaxf(acc[mi][ni][r] + bias1[col], 0.f);
                tbuf[lr][col] = f2b(v);
            }
        }
    __syncthreads();

    // stage 2: T@W2^T + b2 -> Z (fp32), A-frags from LDS
#pragma unroll
    for (int mi = 0; mi < 4; mi++)
#pragma unroll
        for (int ni = 0; ni < 4; ni++)
#pragma unroll
            for (int r = 0; r < 4; r++) acc[mi][ni][r] = 0.f;

#pragma unroll
    for (int ks = 0; ks < 4; ++ks) {
        short8 af[4], bf[4];
#pragma unroll
        for (int mi = 0; mi < 4; mi++)
            af[mi] = *(const short8*)&tbuf[r0 + mi * 16 + l16][ks * 32 + quad * 8];
#pragma unroll
        for (int ni = 0; ni < 4; ni++) {
            int nb = (c0 >> 4) + ni;
            bf[ni] = *(const short8*)(W2b + ((size_t)(nb * 4 + ks) * 64 + lane) * 8);
        }
#pragma unroll
        for (int mi = 0; mi < 4; mi++)
#pragma unroll
            for (int ni = 0; ni < 4; ni++)
                acc[mi][ni] = __builtin_amdgcn_mfma_f32_16x16x32_bf16(
                    af[mi], bf[ni], acc[mi][ni], 0, 0, 0);
    }
#pragma unroll
    for (int mi = 0; mi < 4; mi++)
#pragma unroll
        for (int r = 0; r < 4; r++) {
            int gr = rowBase + r0 + mi * 16 + quad * 4 + r;
            if (gr >= N) continue;
#pragma unroll
            for (int ni = 0; ni < 4; ni++) {
                int col = c0 + ni * 16 + l16;
                Z[(size_t)gr * 128 + col] = acc[mi][ni][r] + bias2[col];
            }
        }
}

extern "C" void kernel_launch(void* const* d_in, const int* in_sizes, int n_in,
                              void* d_out, int out_size, void* d_ws, size_t ws_size,
                              hipStream_t stream)
{
    const float* x   = (const float*)d_in[0];
    const int*   ei  = (const int*)d_in[1];
    const float* ew  = (const float*)d_in[2];
    const float* W1  = (const float*)d_in[3];
    const float* b1  = (const float*)d_in[4];
    const float* W2  = (const float*)d_in[5];
    const float* b2  = (const float*)d_in[6];
    const float* W3  = (const float*)d_in[7];
    const float* b3  = (const float*)d_in[8];
    const float* g1  = (const float*)d_in[9];
    const float* be1 = (const float*)d_in[10];
    const float* g2  = (const float*)d_in[11];
    const float* be2 = (const float*)d_in[12];
    const float* pW1 = (const float*)d_in[13];
    const float* pb1 = (const float*)d_in[14];
    const float* pW2 = (const float*)d_in[15];
    const float* pb2 = (const float*)d_in[16];

    const int N = in_sizes[0] / NF;
    const int E = in_sizes[2];

    float* out_logits = (float*)d_out;
    float* out_h      = out_logits + (size_t)N * 64;
    float* out_z      = out_h + (size_t)N * NF;

    // ---- workspace layout ----
    const size_t rowsUS = (size_t)N * NF;
    int2*           epk = (int2*)d_ws;                           // E*8 B
    unsigned short* B1  = (unsigned short*)(epk + E);            // xb -> pre2b
    unsigned short* B2  = B1 + rowsUS;                           // tmp -> p0/p1 -> hb
    unsigned short* B3  = B2 + rowsUS;                           // pre1 -> y -> t
    float* stats1 = (float*)(B3 + rowsUS);                       // 256 f
    float* stats2 = stats1 + 256;                                // 256 f
    int*   bcur   = (int*)(stats2 + 256);                        // 512 i (one memset covers stats1..bcur)
    int*   bbase  = bcur + 512;                                  // 512 i
    unsigned short* W1b  = (unsigned short*)(bbase + 512);       // 128*128
    unsigned short* W2b  = W1b + 128 * 128;
    unsigned short* pW1b = W2b + 128 * 128;
    unsigned short* pW2b = pW1b + 128 * 128;
    unsigned short* W3b  = pW2b + 128 * 128;                     // 64*128
    int* off = (int*)(W3b + 64 * 128);                           // N+1
    int2* tmp = (int2*)B2;    // fixed-cap bucket regions: nbuk*BCAP*8 B
                              // (391*6144*8 = 19.2 MB <= 25.6 MB; dead before
                              //  gather#1 writes B2 — serial stream)

    const int nbuk   = (N + 255) >> 8;
    const int ggrid  = (N + 127) / 128;
    const int pgrid  = (N + 3) / 4;
    const int c4grid = (N * NF / 4 + 255) / 256;
    const int e4grid = (E + 4095) / 4096;
    const float invN = 1.f / (float)N;

    // ---- one memset: stats1 | stats2 | bcur ----
    hipMemsetAsync(stats1, 0, (2 * 256) * sizeof(float) + 512 * sizeof(int), stream);

    // ---- converts ----
    convx_k<<<c4grid, 256, 0, stream>>>(x, B1, N * NF / 4);
    convw_all_k<<<176, 64, 0, stream>>>(W1, W2, pW1, pW2, W3,
                                        W1b, W2b, pW1b, pW2b, W3b);

    // ---- CSR build (fixed-capacity bucketed counting sort; no bhist) ----
    filla2_k<<<e4grid, 512, 0, stream>>>(ei, ew, bcur, tmp, E);
    bscan_k<<<1, 512, 0, stream>>>(bcur, bbase, nbuk);
    fillb_k<<<nbuk, 512, 0, stream>>>(tmp, bbase, bcur, off, epk, N, E, nbuk);

    // ---- layer 1 ----
    gather_k<0><<<pgrid, 256, 0, stream>>>(B1, off, epk, B2, N,
                                           nullptr, nullptr, nullptr, 0.f);
    mgemm_k<128, 1><<<ggrid, 256, 0, stream>>>(B2, W1b, b1, B3, N, 0, stats1);

    // ---- layer 2 (BN1+ReLU fused into gather load) ----
    gather_k<1><<<pgrid, 256, 0, stream>>>(B3, off, epk, B2, N,
                                           stats1, g1, be1, invN);
    mgemm_k<128, 1><<<ggrid, 256, 0, stream>>>(B2, W2b, b2, B1, N, 0, stats2);

    // ---- BN2+ReLU -> out_h (fp32) + hb (bf16, into B2) ----
    bnrelu2_k<<<c4grid, 256, 0, stream>>>(B1, stats2, g2, be2, out_h, B2,
                                          N * NF / 4, invN);

    // ---- logits = propagate(h @ W3^T) + b3 ----
    mgemm_k<64, 1><<<ggrid, 256, 0, stream>>>(B2, W3b, nullptr, B3, N, 0, nullptr);
    gather64_k<<<pgrid, 256, 0, stream>>>(B3, off, epk, b3, out_logits, N);

    // ---- proj MLP fused: z = relu(h@pW1.T+pb1) @ pW2.T + pb2 ----
    projf_k<<<ggrid, 256, 0, stream>>>(B2, pW1b, pb1, pW2b, pb2, out_z, N);
}

// Round 9
// 587.469 us; speedup vs baseline: 1.3567x; 1.0031x over previous
//
#include <hip/hip_runtime.h>

// SGGCN forward, round 13 (= round 12 resubmitted; r12 bench was an infra
// failure -- "MI355X container failed twice" -- no kernel signal):
//  - gather_k / gather64_k: packed-fp32 inner loop (v_pk_fma_f32 via
//    __builtin_elementwise_fma on float2); bf16 pair decode d<<16 /
//    d&0xffff0000 (same bits as b2f). BIT-IDENTICAL accumulation.
//    r11 counters: gather VALU-issue-bound (VALUBusy 76%, HBM 34%) ->
//    cut instr/edge 16->12 (noBN), 32->24 (BN).
//  - projf3_k: W3 GEMM folded into proj-MLP kernel (y bit-identical);
//    -1 launch, -1 A pass.
//  - everything else: round-11 verbatim (fixed-cap bucketed CSR, mgemm<128>,
//    bnrelu2, convx/convw_all).

#define NF 128
#define BCAP 6144

using short8   = __attribute__((ext_vector_type(8))) short;
using ushort8v = __attribute__((ext_vector_type(8))) unsigned short;
using uint4v   = __attribute__((ext_vector_type(4))) unsigned int;
using uint2v   = __attribute__((ext_vector_type(2))) unsigned int;
using f32x4    = __attribute__((ext_vector_type(4))) float;
using f32x2    = __attribute__((ext_vector_type(2))) float;

__device__ __forceinline__ float b2f(unsigned short u) {
    return __uint_as_float(((unsigned)u) << 16);
}
__device__ __forceinline__ unsigned short f2b(float f) {
    unsigned u = __float_as_uint(f);
    u += 0x7fff + ((u >> 16) & 1);          // RNE
    return (unsigned short)(u >> 16);
}

// ================= CSR build (bucketed, fixed-capacity) =================
__global__ __launch_bounds__(512) void filla2_k(const int* __restrict__ ei,
                                                const float* __restrict__ ew,
                                                int* __restrict__ bcur,
                                                int2* __restrict__ tmp, int E)
{
    __shared__ int dstg[4096];
    __shared__ int cnt[512];
    __shared__ int base[512];
    int t = threadIdx.x;
    cnt[t] = 0;
    __syncthreads();
    int e0 = blockIdx.x * 4096;
    int eend = min(e0 + 4096, E);
    int n = eend - e0;
    for (int i = t; i < n; i += 512) {
        int d = ei[E + e0 + i];
        dstg[i] = d;
        atomicAdd(&cnt[d >> 8], 1);
    }
    __syncthreads();
    {
        int c = cnt[t];
        base[t] = c ? (t * BCAP + atomicAdd(&bcur[t], c)) : 0;  // claim run
        cnt[t] = 0;
    }
    __syncthreads();
    for (int i = t; i < n; i += 512) {
        int d = dstg[i];
        int b = d >> 8;
        int r = atomicAdd(&cnt[b], 1);             // LDS rank within run
        int2 q;
        q.x = (int)(((unsigned)ei[e0 + i]) | (((unsigned)(d & 255)) << 24));
        q.y = __float_as_int(ew[e0 + i]);
        tmp[base[b] + r] = q;
    }
}

__global__ __launch_bounds__(512) void bscan_k(const int* __restrict__ bcnt,
                                               int* __restrict__ bbase, int nbuk)
{
    __shared__ int sc[512];
    int t = threadIdx.x;
    int v = (t < nbuk) ? bcnt[t] : 0;
    sc[t] = v;
    __syncthreads();
    for (int ofs = 1; ofs < 512; ofs <<= 1) {
        int x = (t >= ofs) ? sc[t - ofs] : 0;
        __syncthreads();
        sc[t] += x;
        __syncthreads();
    }
    if (t < nbuk) bbase[t] = sc[t] - v;            // exclusive
}

__global__ __launch_bounds__(512) void fillb_k(const int2* __restrict__ tmp,
                                               const int* __restrict__ bbase,
                                               const int* __restrict__ bcnt,
                                               int* __restrict__ off,
                                               int2* __restrict__ epk,
                                               int N, int E, int nbuk)
{
    __shared__ int lcnt[256];
    __shared__ int lcur[256];
    int t = threadIdx.x;
    int b = blockIdx.x;
    int lo = b << 8;
    int nn = min(256, N - lo);
    if (t < 256) lcnt[t] = 0;
    __syncthreads();
    const int2* src = tmp + (size_t)b * BCAP;
    int cntb = bcnt[b];
    int s = bbase[b];
    for (int i = t; i < cntb; i += 512)
        atomicAdd(&lcnt[((unsigned)src[i].x) >> 24], 1);
    __syncthreads();
    int v = (t < 256) ? lcnt[t] : 0;
    for (int ofs = 1; ofs < 256; ofs <<= 1) {       // inclusive Hillis-Steele
        int x = (t >= ofs && t < 256) ? lcnt[t - ofs] : 0;
        __syncthreads();
        if (t < 256) lcnt[t] += x;
        __syncthreads();
    }
    if (t < 256) {
        int st = s + lcnt[t] - v;                   // exclusive + bucket base
        lcur[t] = st;
        if (t < nn) off[lo + t] = st;
    }
    if (b == 0 && t == 0) off[N] = E;
    __syncthreads();
    for (int i = t; i < cntb; i += 512) {
        int2 q = src[i];
        unsigned qx = (unsigned)q.x;
        int pos = atomicAdd(&lcur[qx >> 24], 1);    // LDS cursor
        int2 o;
        o.x = (int)(qx & 0xFFFFFF);
        o.y = q.y;
        epk[pos] = o;
    }
}

// ================= converts =================
__global__ __launch_bounds__(256) void convx_k(const float* __restrict__ x,
                                               unsigned short* __restrict__ xb,
                                               int total4)
{
    int idx = blockIdx.x * 256 + threadIdx.x;
    if (idx >= total4) return;
    float4 v = *(const float4*)&x[(size_t)idx * 4];
    ushort4 o;
    o.x = f2b(v.x); o.y = f2b(v.y); o.z = f2b(v.z); o.w = f2b(v.w);
    *(ushort4*)&xb[(size_t)idx * 4] = o;
}

__global__ __launch_bounds__(64) void convw_all_k(
    const float* __restrict__ W1,  const float* __restrict__ W2,
    const float* __restrict__ pW1, const float* __restrict__ pW2,
    const float* __restrict__ W3,
    unsigned short* __restrict__ W1b,  unsigned short* __restrict__ W2b,
    unsigned short* __restrict__ pW1b, unsigned short* __restrict__ pW2b,
    unsigned short* __restrict__ W3b)
{
    int bid = blockIdx.x;                          // 0..175
    const float* W; unsigned short* Wb; int lb;
    if      (bid < 32)  { W = W1;  Wb = W1b;  lb = bid; }
    else if (bid < 64)  { W = W2;  Wb = W2b;  lb = bid - 32; }
    else if (bid < 96)  { W = pW1; Wb = pW1b; lb = bid - 64; }
    else if (bid < 128) { W = pW2; Wb = pW2b; lb = bid - 96; }
    else                { W = W3;  Wb = W3b;  lb = bid - 128; }
    int lane = threadIdx.x;
    int nb = lb >> 2, ks = lb & 3;
    const float* src = W + (size_t)(nb * 16 + (lane & 15)) * 128 + ks * 32 + (lane >> 4) * 8;
    unsigned short* dst = Wb + ((size_t)lb * 64 + lane) * 8;
#pragma unroll
    for (int j = 0; j < 8; j++) dst[j] = f2b(src[j]);
}

// ====== gather propagate, 4 edge-streams/wave, packed-fp32 inner loop ======
// One row per wave (4 waves/block). half = lane>>4 picks edge stream 0..3,
// sub = lane&15 covers 8 cols (4 dwords = 16B). Conversion: bf16 pair in
// dword d -> lo = d<<16, hi = d&0xffff0000 (identical bits to b2f).
// acc via v_pk_fma_f32 (__builtin_elementwise_fma on f32x2) -- bit-identical.
template <int BN>
__global__ __launch_bounds__(256) void gather_k(
    const unsigned short* __restrict__ h, const int* __restrict__ off,
    const int2* __restrict__ epk, unsigned short* __restrict__ p, int N,
    const float* __restrict__ bnstats, const float* __restrict__ g,
    const float* __restrict__ be, float invN)
{
    int row = blockIdx.x * 4 + (threadIdx.x >> 6);
    if (row >= N) return;
    int lane = threadIdx.x & 63;
    int half = lane >> 4;          // edge stream 0..3
    int sub  = lane & 15;
    int c0 = sub * 8;

    f32x2 sc2[4], sh2[4];
    if (BN) {
#pragma unroll
        for (int j = 0; j < 8; j++) {
            float m = bnstats[c0 + j] * invN;
            float v = bnstats[NF + c0 + j] * invN - m * m;
            float r = rsqrtf(v + 1e-5f) * g[c0 + j];
            sc2[j >> 1][j & 1] = r;
            sh2[j >> 1][j & 1] = be[c0 + j] - m * r;
        }
    }

    int beg = off[row], end = off[row + 1];
    f32x2 acc2[4];
#pragma unroll
    for (int j = 0; j < 4; j++) { acc2[j][0] = 0.f; acc2[j][1] = 0.f; }

#define PROC_EDGE(qq, uu)                                                     \
    {                                                                         \
        float w = __int_as_float((qq).y);                                     \
        f32x2 w2; w2[0] = w; w2[1] = w;                                       \
        _Pragma("unroll")                                                     \
        for (int j = 0; j < 4; j++) {                                         \
            unsigned d = (uu)[j];                                             \
            f32x2 v;                                                          \
            v[0] = __uint_as_float(d << 16);                                  \
            v[1] = __uint_as_float(d & 0xffff0000u);                          \
            if (BN) {                                                         \
                v = __builtin_elementwise_fma(v, sc2[j], sh2[j]);             \
                v[0] = fmaxf(v[0], 0.f);                                      \
                v[1] = fmaxf(v[1], 0.f);                                      \
            }                                                                 \
            acc2[j] = __builtin_elementwise_fma(v, w2, acc2[j]);              \
        }                                                                     \
    }

    int e = beg;
    for (; e + 16 <= end; e += 16) {
        int2 q0 = epk[e + 0 + half],  q1 = epk[e + 4 + half];
        int2 q2 = epk[e + 8 + half],  q3 = epk[e + 12 + half];
        uint4v u0 = *(const uint4v*)&h[(size_t)q0.x * NF + c0];
        uint4v u1 = *(const uint4v*)&h[(size_t)q1.x * NF + c0];
        uint4v u2 = *(const uint4v*)&h[(size_t)q2.x * NF + c0];
        uint4v u3 = *(const uint4v*)&h[(size_t)q3.x * NF + c0];
        PROC_EDGE(q0, u0); PROC_EDGE(q1, u1);
        PROC_EDGE(q2, u2); PROC_EDGE(q3, u3);
    }
    for (; e + 4 <= end; e += 4) {
        int2 q = epk[e + half];
        uint4v u = *(const uint4v*)&h[(size_t)q.x * NF + c0];
        PROC_EDGE(q, u);
    }
    if (half < end - e) {                          // tail: 0..3 edges
        int2 q = epk[e + half];
        uint4v u = *(const uint4v*)&h[(size_t)q.x * NF + c0];
        PROC_EDGE(q, u);
    }
#undef PROC_EDGE

    float a[8];
#pragma unroll
    for (int j = 0; j < 4; j++) { a[2 * j] = acc2[j][0]; a[2 * j + 1] = acc2[j][1]; }
#pragma unroll
    for (int j = 0; j < 8; j++) {
        a[j] += __shfl_xor(a[j], 16);
        a[j] += __shfl_xor(a[j], 32);
    }

    if (half == 0) {
        ushort8v o;
#pragma unroll
        for (int j = 0; j < 8; j++) o[j] = f2b(a[j]);
        *(ushort8v*)&p[(size_t)row * NF + c0] = o;
    }
}

// ====== gather over 64-dim bf16 rows -> fp32 logits + bias (packed) ======
// 1 row/wave, 4 edge-streams x 16 lanes x 2 dwords (8B).
__global__ __launch_bounds__(256) void gather64_k(
    const unsigned short* __restrict__ y, const int* __restrict__ off,
    const int2* __restrict__ epk, const float* __restrict__ bias,
    float* __restrict__ out, int N)
{
    int row = blockIdx.x * 4 + (threadIdx.x >> 6);
    if (row >= N) return;
    int lane = threadIdx.x & 63;
    int str = lane >> 4;           // edge stream 0..3
    int sub = lane & 15;
    int c0 = sub * 4;

    int beg = off[row], end = off[row + 1];
    f32x2 acc2[2];
    acc2[0][0] = 0.f; acc2[0][1] = 0.f; acc2[1][0] = 0.f; acc2[1][1] = 0.f;

#define PROC_E64(qq, uu)                                                      \
    {                                                                         \
        float w = __int_as_float((qq).y);                                     \
        f32x2 w2; w2[0] = w; w2[1] = w;                                       \
        _Pragma("unroll")                                                     \
        for (int j = 0; j < 2; j++) {                                         \
            unsigned d = (uu)[j];                                             \
            f32x2 v;                                                          \
            v[0] = __uint_as_float(d << 16);                                  \
            v[1] = __uint_as_float(d & 0xffff0000u);                          \
            acc2[j] = __builtin_elementwise_fma(v, w2, acc2[j]);              \
        }                                                                     \
    }

    int e = beg;
    for (; e + 16 <= end; e += 16) {
        int2 q0 = epk[e + 0 + str],  q1 = epk[e + 4 + str];
        int2 q2 = epk[e + 8 + str],  q3 = epk[e + 12 + str];
        uint2v u0 = *(const uint2v*)&y[(size_t)q0.x * 64 + c0];
        uint2v u1 = *(const uint2v*)&y[(size_t)q1.x * 64 + c0];
        uint2v u2 = *(const uint2v*)&y[(size_t)q2.x * 64 + c0];
        uint2v u3 = *(const uint2v*)&y[(size_t)q3.x * 64 + c0];
        PROC_E64(q0, u0); PROC_E64(q1, u1);
        PROC_E64(q2, u2); PROC_E64(q3, u3);
    }
    for (; e + 4 <= end; e += 4) {
        int2 q = epk[e + str];
        uint2v u = *(const uint2v*)&y[(size_t)q.x * 64 + c0];
        PROC_E64(q, u);
    }
    if (str < end - e) {                           // tail: 0..3 edges
        int2 q = epk[e + str];
        uint2v u = *(const uint2v*)&y[(size_t)q.x * 64 + c0];
        PROC_E64(q, u);
    }
#undef PROC_E64

    float a[4] = {acc2[0][0], acc2[0][1], acc2[1][0], acc2[1][1]};
#pragma unroll
    for (int j = 0; j < 4; j++) {
        a[j] += __shfl_xor(a[j], 16);
        a[j] += __shfl_xor(a[j], 32);
    }

    if (lane < 16) {
        float4 o;
        o.x = a[0] + bias[c0];     o.y = a[1] + bias[c0 + 1];
        o.z = a[2] + bias[c0 + 2]; o.w = a[3] + bias[c0 + 3];
        *(float4*)&out[(size_t)row * 64 + c0] = o;
    }
}

// ================= MFMA GEMM: C[N,128] = A[N,128]bf16 @ W^T + b ==========
template <int M, int COUT>
__global__ __launch_bounds__(256) void mgemm_k(
    const unsigned short* __restrict__ A, const unsigned short* __restrict__ Wb,
    const float* __restrict__ bias, void* __restrict__ Cp,
    int N, int relu, float* __restrict__ stats)
{
    constexpr int MI = (M == 128) ? 4 : 2;
    __shared__ float sbuf[256];

    const int tid = threadIdx.x, wid = tid >> 6, lane = tid & 63;
    const int quad = lane >> 4, l16 = lane & 15;
    const int rowBase = blockIdx.x * 128;
    int r0, c0;
    if constexpr (M == 128) { r0 = (wid >> 1) * 64; c0 = (wid & 1) * 64; }
    else                    { r0 = wid * 32;        c0 = 0; }

    f32x4 acc[MI][4];
#pragma unroll
    for (int mi = 0; mi < MI; mi++)
#pragma unroll
        for (int ni = 0; ni < 4; ni++)
#pragma unroll
            for (int r = 0; r < 4; r++) acc[mi][ni][r] = 0.f;

#pragma unroll
    for (int ks = 0; ks < 4; ++ks) {
        short8 af[MI], bf[4];
#pragma unroll
        for (int mi = 0; mi < MI; mi++) {
            int gr = rowBase + r0 + mi * 16 + l16;
            gr = (gr < N) ? gr : (N - 1);
            af[mi] = *(const short8*)(A + (size_t)gr * 128 + ks * 32 + quad * 8);
        }
#pragma unroll
        for (int ni = 0; ni < 4; ni++) {
            int nb = (c0 >> 4) + ni;
            bf[ni] = *(const short8*)(Wb + ((size_t)(nb * 4 + ks) * 64 + lane) * 8);
        }
#pragma unroll
        for (int mi = 0; mi < MI; mi++)
#pragma unroll
            for (int ni = 0; ni < 4; ni++)
                acc[mi][ni] = __builtin_amdgcn_mfma_f32_16x16x32_bf16(
                    af[mi], bf[ni], acc[mi][ni], 0, 0, 0);
    }

    float csum[4] = {0.f, 0.f, 0.f, 0.f}, csq[4] = {0.f, 0.f, 0.f, 0.f};
#pragma unroll
    for (int mi = 0; mi < MI; mi++) {
#pragma unroll
        for (int r = 0; r < 4; r++) {
            int gr = rowBase + r0 + mi * 16 + quad * 4 + r;
            if (gr >= N) continue;
#pragma unroll
            for (int ni = 0; ni < 4; ni++) {
                int col = c0 + ni * 16 + l16;
                float v = acc[mi][ni][r] + (bias ? bias[col] : 0.f);
                if (relu) v = fmaxf(v, 0.f);
                if constexpr (COUT == 1)
                    ((unsigned short*)Cp)[(size_t)gr * M + col] = f2b(v);
                else
                    ((float*)Cp)[(size_t)gr * M + col] = v;
                csum[ni] += v;
                csq[ni]  += v * v;
            }
        }
    }

    if (stats) {
        sbuf[tid] = 0.f;
        __syncthreads();
#pragma unroll
        for (int ni = 0; ni < 4; ni++) {
            int col = c0 + ni * 16 + l16;
            atomicAdd(&sbuf[col], csum[ni]);
            atomicAdd(&sbuf[128 + col], csq[ni]);
        }
        __syncthreads();
        if (tid < 128) {
            unsafeAtomicAdd(&stats[tid], sbuf[tid]);
            unsafeAtomicAdd(&stats[NF + tid], sbuf[128 + tid]);
        }
    }
}

// ======= BN2 + affine + ReLU: bf16 pre -> fp32 out_h AND bf16 hb ==========
__global__ __launch_bounds__(256) void bnrelu2_k(
    const unsigned short* __restrict__ pre, const float* __restrict__ stats,
    const float* __restrict__ g, const float* __restrict__ be,
    float* __restrict__ outh, unsigned short* __restrict__ hb,
    int total4, float invN)
{
    int idx = blockIdx.x * 256 + threadIdx.x;
    if (idx >= total4) return;
    int c = (idx * 4) & 127;
    ushort4 u = *(const ushort4*)&pre[(size_t)idx * 4];
    float in[4] = {b2f(u.x), b2f(u.y), b2f(u.z), b2f(u.w)};
    float o[4];
#pragma unroll
    for (int i = 0; i < 4; i++) {
        float m   = stats[c + i] * invN;
        float var = stats[NF + c + i] * invN - m * m;
        float rs  = rsqrtf(var + 1e-5f);
        o[i] = fmaxf((in[i] - m) * rs * g[c + i] + be[c + i], 0.f);
    }
    float4 f; f.x = o[0]; f.y = o[1]; f.z = o[2]; f.w = o[3];
    *(float4*)&outh[(size_t)idx * 4] = f;
    ushort4 h4;
    h4.x = f2b(o[0]); h4.y = f2b(o[1]); h4.z = f2b(o[2]); h4.w = f2b(o[3]);
    *(ushort4*)&hb[(size_t)idx * 4] = h4;
}

// == fused y=A@W3^T (bf16) + proj MLP z=relu(A@pW1^T+pb1)@pW2^T+pb2 ==
// Stage Y: mgemm64_k verbatim (r0=wid*32 mapping) -> y bit-identical; A tile
// is L2-hot for the subsequent proj stages. Stages 1/2: projf_k verbatim.
__global__ __launch_bounds__(256) void projf3_k(
    const unsigned short* __restrict__ A, const unsigned short* __restrict__ W1b,
    const float* __restrict__ bias1, const unsigned short* __restrict__ W2b,
    const float* __restrict__ bias2, const unsigned short* __restrict__ W3b,
    float* __restrict__ Z, unsigned short* __restrict__ Y, int N)
{
    __shared__ unsigned short tbuf[128][136];

    const int tid = threadIdx.x, wid = tid >> 6, lane = tid & 63;
    const int quad = lane >> 4, l16 = lane & 15;
    const int rowBase = blockIdx.x * 128;

    // ---- stage Y: y = bf16(A @ W3^T), 4 waves x 32-row strips ----
    {
        const int r0y = wid * 32;
        f32x4 acy[2][4];
#pragma unroll
        for (int mi = 0; mi < 2; mi++)
#pragma unroll
            for (int ni = 0; ni < 4; ni++)
#pragma unroll
                for (int r = 0; r < 4; r++) acy[mi][ni][r] = 0.f;

#pragma unroll
        for (int ks = 0; ks < 4; ++ks) {
            short8 af[2], bf[4];
#pragma unroll
            for (int mi = 0; mi < 2; mi++) {
                int gr = rowBase + r0y + mi * 16 + l16;
                gr = (gr < N) ? gr : (N - 1);
                af[mi] = *(const short8*)(A + (size_t)gr * 128 + ks * 32 + quad * 8);
            }
#pragma unroll
            for (int ni = 0; ni < 4; ni++)
                bf[ni] = *(const short8*)(W3b + ((size_t)(ni * 4 + ks) * 64 + lane) * 8);
#pragma unroll
            for (int mi = 0; mi < 2; mi++)
#pragma unroll
                for (int ni = 0; ni < 4; ni++)
                    acy[mi][ni] = __builtin_amdgcn_mfma_f32_16x16x32_bf16(
                        af[mi], bf[ni], acy[mi][ni], 0, 0, 0);
        }

#pragma unroll
        for (int mi = 0; mi < 2; mi++)
#pragma unroll
            for (int r = 0; r < 4; r++) {
                int gr = rowBase + r0y + mi * 16 + quad * 4 + r;
                if (gr >= N) continue;
#pragma unroll
                for (int ni = 0; ni < 4; ni++) {
                    int col = ni * 16 + l16;
                    Y[(size_t)gr * 64 + col] = f2b(acy[mi][ni][r] + 0.f);
                }
            }
    }

    // ---- stages 1/2: proj MLP (projf_k verbatim) ----
    const int r0 = (wid >> 1) * 64, c0 = (wid & 1) * 64;

    f32x4 acc[4][4];
#pragma unroll
    for (int mi = 0; mi < 4; mi++)
#pragma unroll
        for (int ni = 0; ni < 4; ni++)
#pragma unroll
            for (int r = 0; r < 4; r++) acc[mi][ni][r] = 0.f;

    // stage 1: relu(A@W1^T + b1) -> LDS (bf16)
#pragma unroll
    for (int ks = 0; ks < 4; ++ks) {
        short8 af[4], bf[4];
#pragma unroll
        for (int mi = 0; mi < 4; mi++) {
            int gr = rowBase + r0 + mi * 16 + l16;
            gr = (gr < N) ? gr : (N - 1);
            af[mi] = *(const short8*)(A + (size_t)gr * 128 + ks * 32 + quad * 8);
        }
#pragma unroll
        for (int ni = 0; ni < 4; ni++) {
            int nb = (c0 >> 4) + ni;
            bf[ni] = *(const short8*)(W1b + ((size_t)(nb * 4 + ks) * 64 + lane) * 8);
        }
#pragma unroll
        for (int mi = 0; mi < 4; mi++)
#pragma unroll
            for (int ni = 0; ni < 4; ni++)
                acc[mi][ni] = __builtin_amdgcn_mfma_f32_16x16x32_bf16(
                    af[mi], bf[ni], acc[mi][ni], 0, 0, 0);
    }
#pragma unroll
    for (int mi = 0; mi < 4; mi++)
#pragma unroll
        for (int r = 0; r < 4; r++) {
            int lr = r0 + mi * 16 + quad * 4 + r;
#pragma unroll
            for (int ni = 0; ni < 4; ni++) {
                int col = c0 + ni * 16 + l16;
                float v = fmaxf(acc[mi][ni][r] + bias1[col], 0.f);
                tbuf[lr][col] = f2b(v);
            }
        }
    __syncthreads();

    // stage 2: T@W2^T + b2 -> Z (fp32), A-frags from LDS
#pragma unroll
    for (int mi = 0; mi < 4; mi++)
#pragma unroll
        for (int ni = 0; ni < 4; ni++)
#pragma unroll
            for (int r = 0; r < 4; r++) acc[mi][ni][r] = 0.f;

#pragma unroll
    for (int ks = 0; ks < 4; ++ks) {
        short8 af[4], bf[4];
#pragma unroll
        for (int mi = 0; mi < 4; mi++)
            af[mi] = *(const short8*)&tbuf[r0 + mi * 16 + l16][ks * 32 + quad * 8];
#pragma unroll
        for (int ni = 0; ni < 4; ni++) {
            int nb = (c0 >> 4) + ni;
            bf[ni] = *(const short8*)(W2b + ((size_t)(nb * 4 + ks) * 64 + lane) * 8);
        }
#pragma unroll
        for (int mi = 0; mi < 4; mi++)
#pragma unroll
            for (int ni = 0; ni < 4; ni++)
                acc[mi][ni] = __builtin_amdgcn_mfma_f32_16x16x32_bf16(
                    af[mi], bf[ni], acc[mi][ni], 0, 0, 0);
    }
#pragma unroll
    for (int mi = 0; mi < 4; mi++)
#pragma unroll
        for (int r = 0; r < 4; r++) {
            int gr = rowBase + r0 + mi * 16 + quad * 4 + r;
            if (gr >= N) continue;
#pragma unroll
            for (int ni = 0; ni < 4; ni++) {
                int col = c0 + ni * 16 + l16;
                Z[(size_t)gr * 128 + col] = acc[mi][ni][r] + bias2[col];
            }
        }
}

extern "C" void kernel_launch(void* const* d_in, const int* in_sizes, int n_in,
                              void* d_out, int out_size, void* d_ws, size_t ws_size,
                              hipStream_t stream)
{
    const float* x   = (const float*)d_in[0];
    const int*   ei  = (const int*)d_in[1];
    const float* ew  = (const float*)d_in[2];
    const float* W1  = (const float*)d_in[3];
    const float* b1  = (const float*)d_in[4];
    const float* W2  = (const float*)d_in[5];
    const float* b2  = (const float*)d_in[6];
    const float* W3  = (const float*)d_in[7];
    const float* b3  = (const float*)d_in[8];
    const float* g1  = (const float*)d_in[9];
    const float* be1 = (const float*)d_in[10];
    const float* g2  = (const float*)d_in[11];
    const float* be2 = (const float*)d_in[12];
    const float* pW1 = (const float*)d_in[13];
    const float* pb1 = (const float*)d_in[14];
    const float* pW2 = (const float*)d_in[15];
    const float* pb2 = (const float*)d_in[16];

    const int N = in_sizes[0] / NF;
    const int E = in_sizes[2];

    float* out_logits = (float*)d_out;
    float* out_h      = out_logits + (size_t)N * 64;
    float* out_z      = out_h + (size_t)N * NF;

    // ---- workspace layout ----
    const size_t rowsUS = (size_t)N * NF;
    int2*           epk = (int2*)d_ws;                           // E*8 B
    unsigned short* B1  = (unsigned short*)(epk + E);            // xb -> pre2b
    unsigned short* B2  = B1 + rowsUS;                           // tmp -> p0/p1 -> hb
    unsigned short* B3  = B2 + rowsUS;                           // pre1 -> y
    float* stats1 = (float*)(B3 + rowsUS);                       // 256 f
    float* stats2 = stats1 + 256;                                // 256 f
    int*   bcur   = (int*)(stats2 + 256);                        // 512 i
    int*   bbase  = bcur + 512;                                  // 512 i
    unsigned short* W1b  = (unsigned short*)(bbase + 512);       // 128*128
    unsigned short* W2b  = W1b + 128 * 128;
    unsigned short* pW1b = W2b + 128 * 128;
    unsigned short* pW2b = pW1b + 128 * 128;
    unsigned short* W3b  = pW2b + 128 * 128;                     // 64*128
    int* off = (int*)(W3b + 64 * 128);                           // N+1
    int2* tmp = (int2*)B2;    // fixed-cap bucket regions: nbuk*BCAP*8 B
                              // (391*6144*8 = 19.2 MB <= 25.6 MB; dead before
                              //  gather#1 writes B2 -- serial stream)

    const int nbuk   = (N + 255) >> 8;
    const int ggrid  = (N + 127) / 128;
    const int pgrid  = (N + 3) / 4;
    const int c4grid = (N * NF / 4 + 255) / 256;
    const int e4grid = (E + 4095) / 4096;
    const float invN = 1.f / (float)N;

    // ---- one memset: stats1 | stats2 | bcur ----
    hipMemsetAsync(stats1, 0, (2 * 256) * sizeof(float) + 512 * sizeof(int), stream);

    // ---- converts ----
    convx_k<<<c4grid, 256, 0, stream>>>(x, B1, N * NF / 4);
    convw_all_k<<<176, 64, 0, stream>>>(W1, W2, pW1, pW2, W3,
                                        W1b, W2b, pW1b, pW2b, W3b);

    // ---- CSR build (fixed-capacity bucketed counting sort) ----
    filla2_k<<<e4grid, 512, 0, stream>>>(ei, ew, bcur, tmp, E);
    bscan_k<<<1, 512, 0, stream>>>(bcur, bbase, nbuk);
    fillb_k<<<nbuk, 512, 0, stream>>>(tmp, bbase, bcur, off, epk, N, E, nbuk);

    // ---- layer 1 ----
    gather_k<0><<<pgrid, 256, 0, stream>>>(B1, off, epk, B2, N,
                                           nullptr, nullptr, nullptr, 0.f);
    mgemm_k<128, 1><<<ggrid, 256, 0, stream>>>(B2, W1b, b1, B3, N, 0, stats1);

    // ---- layer 2 (BN1+ReLU fused into gather load) ----
    gather_k<1><<<pgrid, 256, 0, stream>>>(B3, off, epk, B2, N,
                                           stats1, g1, be1, invN);
    mgemm_k<128, 1><<<ggrid, 256, 0, stream>>>(B2, W2b, b2, B1, N, 0, stats2);

    // ---- BN2+ReLU -> out_h (fp32) + hb (bf16, into B2) ----
    bnrelu2_k<<<c4grid, 256, 0, stream>>>(B1, stats2, g2, be2, out_h, B2,
                                          N * NF / 4, invN);

    // ---- fused: y = hb@W3^T (B3) + proj MLP z -> out_z ----
    projf3_k<<<ggrid, 256, 0, stream>>>(B2, pW1b, pb1, pW2b, pb2, W3b,
                                        out_z, B3, N);

    // ---- logits = propagate(y) + b3 ----
    gather64_k<<<pgrid, 256, 0, stream>>>(B3, off, epk, b3, out_logits, N);
}